// Round 6
// baseline (31741.043 us; speedup 1.0000x reference)
//
#include <hip/hip_runtime.h>

// ---------------------------------------------------------------------------
// WeatherModel ConvLSTM enc-dec, fp32, MI355X. Round 6: latency-hiding attack.
// Evidence: R5 neutral (HCPB/CI/traffic changes did nothing) + R3 speedup ==
// FLOP ratio => kernels are latency-exposed at low waves/SIMD, not issue- or
// BW-bound. Changes: (1) conv_lstm 16x16 tiles -> 2048*nb blocks (8 waves/SIMD
// at nb=1, was 2); (2) zpart split-K partials atomicAdd into bias-initialized
// buffer (kills combine_add dispatches + zpp buffer, chain 3->2 per step);
// (3) footprint 96.7 -> 80.3 MB per nb-unit.
// ---------------------------------------------------------------------------

#define PX 16384L   // 128*128
#define T_ 10
#define D_ 10

__device__ __forceinline__ float sigmoidf_(float x) { return 1.f / (1.f + expf(-x)); }

// ============ fused conv3x3 + ConvLSTM gates, 16x16 tile, 1 px/thread ======
// hidden=64. grid: (64, 32, nb). HCPB=2, CI=8. LDS 10.4 KB -> high occupancy.
__global__ __launch_bounds__(256)
void conv_lstm_k(const float* __restrict__ in0, int c0, long bs0, long cst0,
                 const float* __restrict__ in1, int c1, long bs1, long cst1,
                 const float* __restrict__ w, const float* __restrict__ bias, int hidden,
                 const float* __restrict__ cprev, long cpbs,
                 float* __restrict__ hout, long hobs,
                 float* __restrict__ cout_, long cobs)
{
    __shared__ float lds[8][324];              // 18x18 halo per channel
    const int tid = threadIdx.x;
    const int tx = tid & 15, ty = tid >> 4;
    const int tileX = (blockIdx.x & 7) << 4, tileY = (blockIdx.x >> 3) << 4;
    const int b = blockIdx.z;
    const int cin = c0 + c1;
    const int hc0 = blockIdx.y * 2;
    float acc[8];                              // [hc(2)][gate(4)]
#pragma unroll
    for (int j = 0; j < 8; j++) acc[j] = 0.f;

    for (int cb = 0; cb < cin; cb += 8) {
        const int cmax = min(8, cin - cb);
        for (int cl = 0; cl < cmax; cl++) {
            const int ci = cb + cl;
            const float* p = (ci < c0) ? in0 + (long)b * bs0 + (long)ci * cst0
                                       : in1 + (long)b * bs1 + (long)(ci - c0) * cst1;
            for (int idx = tid; idx < 324; idx += 256) {
                const int r = idx / 18, cc = idx - r * 18;
                const int gy = tileY + r - 1, gx = tileX + cc - 1;
                lds[cl][idx] = ((unsigned)gy < 128u && (unsigned)gx < 128u)
                                   ? p[gy * 128 + gx] : 0.f;
            }
        }
        __syncthreads();
        for (int cl = 0; cl < cmax; cl++) {
            float r9[9];
#pragma unroll
            for (int dy = 0; dy < 3; dy++)
#pragma unroll
                for (int dx = 0; dx < 3; dx++)
                    r9[dy * 3 + dx] = lds[cl][(ty + dy) * 18 + tx + dx];
            const int ci = cb + cl;
#pragma unroll
            for (int j = 0; j < 2; j++)
#pragma unroll
                for (int g = 0; g < 4; g++) {
                    const float* wp = w + ((long)(g * hidden + hc0 + j) * cin + ci) * 9;
                    float a = acc[j * 4 + g];
#pragma unroll
                    for (int q = 0; q < 9; q++) a = fmaf(wp[q], r9[q], a);
                    acc[j * 4 + g] = a;
                }
        }
        __syncthreads();
    }
    const long opix = (long)(tileY + ty) * 128 + tileX + tx;
#pragma unroll
    for (int j = 0; j < 2; j++) {
        const int hc = hc0 + j;
        const float i_ = sigmoidf_(acc[j * 4 + 0] + bias[hc]);
        const float f_ = sigmoidf_(acc[j * 4 + 1] + bias[hidden + hc]);
        const float o_ = sigmoidf_(acc[j * 4 + 2] + bias[2 * hidden + hc]);
        const float g_ = tanhf(acc[j * 4 + 3] + bias[3 * hidden + hc]);
        const float cp = cprev[(long)b * cpbs + (long)hc * PX + opix];
        const float c2 = f_ * cp + i_ * g_;
        const float h2 = o_ * tanhf(c2);
        hout[(long)b * hobs + (long)hc * PX + opix] = h2;
        cout_[(long)b * cobs + (long)hc * PX + opix] = c2;
    }
}

// ============ split-K partial conv, 16x16 tile, write partials =============
// grid: (64, nco/COPB, nslices*nb); writes pbuf[((slice*nb+b)*nco+co)*PX+px]
template<int COPB>
__global__ __launch_bounds__(256)
void convp_k(const float* __restrict__ in0, int c0, long bs0, long cst0,
             const float* __restrict__ in1, long bs1, long cst1,
             const float* __restrict__ sc, long sbs, long scst,
             const float* __restrict__ w, int wcin, int wcoff,
             int4 cis, int4 cic,
             float* __restrict__ pbuf, int nco, int nb)
{
    __shared__ float lds[4][324];
    const int tid = threadIdx.x;
    const int tx = tid & 15, ty = tid >> 4;
    const int tileX = (blockIdx.x & 7) << 4, tileY = (blockIdx.x >> 3) << 4;
    const int z = blockIdx.z;
    const int b = z % nb, s = z / nb;
    const int ci0 = (s == 0) ? cis.x : (s == 1) ? cis.y : (s == 2) ? cis.z : cis.w;
    const int cn  = (s == 0) ? cic.x : (s == 1) ? cic.y : (s == 2) ? cic.z : cic.w;
    const int co0 = blockIdx.y * COPB;
    float acc[COPB];
#pragma unroll
    for (int j = 0; j < COPB; j++) acc[j] = 0.f;

    for (int cb = 0; cb < cn; cb += 4) {
        const int cmax = min(4, cn - cb);
        for (int cl = 0; cl < cmax; cl++) {
            const int ci = ci0 + cb + cl;
            const float* p; const float* sp = nullptr;
            if (ci < c0) {
                p = in0 + (long)b * bs0 + (long)ci * cst0;
                if (sc) sp = sc + (long)b * sbs + (long)ci * scst;
            } else {
                p = in1 + (long)b * bs1 + (long)(ci - c0) * cst1;
            }
            for (int idx = tid; idx < 324; idx += 256) {
                const int r = idx / 18, cc = idx - r * 18;
                const int gy = tileY + r - 1, gx = tileX + cc - 1;
                float v = 0.f;
                if ((unsigned)gy < 128u && (unsigned)gx < 128u) {
                    v = p[gy * 128 + gx];
                    if (sp) v *= sp[gy * 128 + gx];
                }
                lds[cl][idx] = v;
            }
        }
        __syncthreads();
        for (int cl = 0; cl < cmax; cl++) {
            float r9[9];
#pragma unroll
            for (int dy = 0; dy < 3; dy++)
#pragma unroll
                for (int dx = 0; dx < 3; dx++)
                    r9[dy * 3 + dx] = lds[cl][(ty + dy) * 18 + tx + dx];
            const int ci = ci0 + cb + cl;
#pragma unroll
            for (int j = 0; j < COPB; j++) {
                const float* wp = w + ((long)(co0 + j) * wcin + wcoff + ci) * 9;
                float a = acc[j];
#pragma unroll
                for (int q = 0; q < 9; q++) a = fmaf(wp[q], r9[q], a);
                acc[j] = a;
            }
        }
        __syncthreads();
    }
    const long opix = (long)(tileY + ty) * 128 + tileX + tx;
#pragma unroll
    for (int j = 0; j < COPB; j++)
        pbuf[(((long)s * nb + b) * nco + co0 + j) * PX + opix] = acc[j];
}

// ============ split-K conv, atomicAdd into bias-initialized out ============
// grid: (64, nco/8, nslices*nb); out[b][nco][PX] += partial
__global__ __launch_bounds__(256)
void convp_at_k(const float* __restrict__ in0, int c0, long bs0, long cst0,
                const float* __restrict__ in1, long bs1, long cst1,
                const float* __restrict__ w, int wcin, int wcoff,
                int4 cis, int4 cic,
                float* __restrict__ out, int nco, int nb)
{
    __shared__ float lds[4][324];
    const int tid = threadIdx.x;
    const int tx = tid & 15, ty = tid >> 4;
    const int tileX = (blockIdx.x & 7) << 4, tileY = (blockIdx.x >> 3) << 4;
    const int z = blockIdx.z;
    const int b = z % nb, s = z / nb;
    const int ci0 = (s == 0) ? cis.x : (s == 1) ? cis.y : (s == 2) ? cis.z : cis.w;
    const int cn  = (s == 0) ? cic.x : (s == 1) ? cic.y : (s == 2) ? cic.z : cic.w;
    const int co0 = blockIdx.y * 8;
    float acc[8];
#pragma unroll
    for (int j = 0; j < 8; j++) acc[j] = 0.f;

    for (int cb = 0; cb < cn; cb += 4) {
        const int cmax = min(4, cn - cb);
        for (int cl = 0; cl < cmax; cl++) {
            const int ci = ci0 + cb + cl;
            const float* p = (ci < c0) ? in0 + (long)b * bs0 + (long)ci * cst0
                                       : in1 + (long)b * bs1 + (long)(ci - c0) * cst1;
            for (int idx = tid; idx < 324; idx += 256) {
                const int r = idx / 18, cc = idx - r * 18;
                const int gy = tileY + r - 1, gx = tileX + cc - 1;
                lds[cl][idx] = ((unsigned)gy < 128u && (unsigned)gx < 128u)
                                   ? p[gy * 128 + gx] : 0.f;
            }
        }
        __syncthreads();
        for (int cl = 0; cl < cmax; cl++) {
            float r9[9];
#pragma unroll
            for (int dy = 0; dy < 3; dy++)
#pragma unroll
                for (int dx = 0; dx < 3; dx++)
                    r9[dy * 3 + dx] = lds[cl][(ty + dy) * 18 + tx + dx];
            const int ci = ci0 + cb + cl;
#pragma unroll
            for (int j = 0; j < 8; j++) {
                const float* wp = w + ((long)(co0 + j) * wcin + wcoff + ci) * 9;
                float a = acc[j];
#pragma unroll
                for (int q = 0; q < 9; q++) a = fmaf(wp[q], r9[q], a);
                acc[j] = a;
            }
        }
        __syncthreads();
    }
    const long opix = (long)(tileY + ty) * 128 + tileX + tx;
#pragma unroll
    for (int j = 0; j < 8; j++)
        atomicAdd(&out[((long)b * nco + co0 + j) * PX + opix], acc[j]);
}

// ============ fill z[...] with per-channel bias ============================
__global__ __launch_bounds__(256)
void zfill_k(float* __restrict__ z, const float* __restrict__ bias, long n, int nco)
{
    const long idx = (long)blockIdx.x * 256 + threadIdx.x;
    if (idx >= n) return;
    const int co = (int)((idx >> 14) % nco);
    z[idx] = bias[co];
}

// ============ combine split-K LSTM gate partials -> h,c,out2 ===============
__global__ __launch_bounds__(256)
void combine_lstm_k(const float* __restrict__ pbuf, int nsl, int hidden,
                    const float* __restrict__ bias,
                    const float* __restrict__ cprev, long cpbs,
                    float* __restrict__ hout, long hobs,
                    float* __restrict__ cout_, long cobs,
                    float* __restrict__ hout2, long ho2bs, int nb)
{
    const long idx = (long)blockIdx.x * 256 + threadIdx.x;
    if (idx >= (long)nb * hidden * PX) return;
    const long px = idx & 16383;
    const long v = idx >> 14;
    const int hc = (int)(v % hidden), b = (int)(v / hidden);
    const int nco = 4 * hidden;
    float g4[4] = {0.f, 0.f, 0.f, 0.f};
    for (int s = 0; s < nsl; s++)
#pragma unroll
        for (int g = 0; g < 4; g++)
            g4[g] += pbuf[(((long)s * nb + b) * nco + g * hidden + hc) * PX + px];
    const float i_ = sigmoidf_(g4[0] + bias[hc]);
    const float f_ = sigmoidf_(g4[1] + bias[hidden + hc]);
    const float o_ = sigmoidf_(g4[2] + bias[2 * hidden + hc]);
    const float g_ = tanhf(g4[3] + bias[3 * hidden + hc]);
    const float cp = cprev[(long)b * cpbs + (long)hc * PX + px];
    const float c2 = f_ * cp + i_ * g_;
    const float h2 = o_ * tanhf(c2);
    hout[(long)b * hobs + (long)hc * PX + px] = h2;
    cout_[(long)b * cobs + (long)hc * PX + px] = c2;
    if (hout2) hout2[(long)b * ho2bs + (long)hc * PX + px] = h2;
}

// ============ fused input-attention score (phase 1, full batch) ============
__global__ __launch_bounds__(256)
void iattn_k(const float* __restrict__ x, const float* __restrict__ A,
             const float* __restrict__ h, const float* __restrict__ c,
             const float* __restrict__ wa1, const float* __restrict__ ba1,
             const float* __restrict__ wa2, const float* __restrict__ ba2,
             float* __restrict__ score)
{
    __shared__ float xl[12][400];              // 12 ch on 20x20 halo
    __shared__ float zl[32][324];              // conv1 out on 18x18
    const int tid = threadIdx.x;
    const int tileX = (blockIdx.x & 7) << 4, tileY = (blockIdx.x >> 3) << 4;
    const int z = blockIdx.z;
    const int b = z & 7, k = z >> 3;

    float* aT = &zl[0][0];                     // 400-float temp (overwritten later)
    for (int idx = tid; idx < 400; idx += 256) {
        const int r = idx / 20, cc = idx - r * 20;
        const int gy = tileY + r - 2, gx = tileX + cc - 2;
        aT[idx] = ((unsigned)gy < 128u && (unsigned)gx < 128u)
                      ? A[((long)b * 10 + k) * PX + gy * 128 + gx] : 0.f;
    }
    __syncthreads();
    for (int ch = 0; ch < 12; ch++) {
        const float* p = (ch < 10) ? x + (((long)b * 10 + ch) * 10 + k) * PX
                       : (ch == 10) ? h + (long)b * PX : c + (long)b * PX;
        for (int idx = tid; idx < 400; idx += 256) {
            const int r = idx / 20, cc = idx - r * 20;
            const int gy = tileY + r - 2, gx = tileX + cc - 2;
            float v = 0.f;
            if ((unsigned)gy < 128u && (unsigned)gx < 128u) {
                v = p[gy * 128 + gx];
                if (ch < 10) v *= aT[idx];
            }
            xl[ch][idx] = v;
        }
    }
    __syncthreads();
    const int i0 = tid, i1 = tid + 256;
    const int zr0 = i0 / 18, zc0 = i0 - zr0 * 18;
    const int zr1 = (i1 < 324) ? i1 / 18 : 0, zc1 = (i1 < 324) ? i1 - (i1 / 18) * 18 : 0;
    float acc0[32], acc1[32];
#pragma unroll
    for (int co = 0; co < 32; co++) { acc0[co] = 0.f; acc1[co] = 0.f; }
    for (int ci = 0; ci < 12; ci++) {
        float wA[9], wB[9];
#pragma unroll
        for (int dy = 0; dy < 3; dy++)
#pragma unroll
            for (int dx = 0; dx < 3; dx++) {
                wA[dy * 3 + dx] = xl[ci][(zr0 + dy) * 20 + zc0 + dx];
                wB[dy * 3 + dx] = xl[ci][(zr1 + dy) * 20 + zc1 + dx];
            }
#pragma unroll
        for (int co = 0; co < 32; co++) {
            const float* wp = wa1 + ((long)co * 12 + ci) * 9;
            float a0 = acc0[co], a1 = acc1[co];
#pragma unroll
            for (int q = 0; q < 9; q++) { a0 = fmaf(wp[q], wA[q], a0); a1 = fmaf(wp[q], wB[q], a1); }
            acc0[co] = a0; acc1[co] = a1;
        }
    }
    __syncthreads();
    {
        const int gy0 = tileY + zr0 - 1, gx0 = tileX + zc0 - 1;
        const bool in0_ = ((unsigned)gy0 < 128u && (unsigned)gx0 < 128u);
        const int gy1 = tileY + zr1 - 1, gx1 = tileX + zc1 - 1;
        const bool in1_ = (i1 < 324) && ((unsigned)gy1 < 128u && (unsigned)gx1 < 128u);
#pragma unroll
        for (int co = 0; co < 32; co++) {
            zl[co][i0] = in0_ ? tanhf(acc0[co] + ba1[co]) : 0.f;
            if (i1 < 324) zl[co][i1] = in1_ ? tanhf(acc1[co] + ba1[co]) : 0.f;
        }
    }
    __syncthreads();
    const int tx = tid & 15, ty = tid >> 4;
    float a = ba2[0];
    for (int co = 0; co < 32; co++) {
#pragma unroll
        for (int ky = 0; ky < 3; ky++)
#pragma unroll
            for (int kx = 0; kx < 3; kx++)
                a = fmaf(wa2[co * 9 + ky * 3 + kx], zl[co][(ty + ky) * 18 + tx + kx], a);
    }
    score[((long)b * 10 + k) * PX + (long)(tileY + ty) * 128 + tileX + tx] = a;
}

// ============ softmax over 10 (+optional compound into A) ==================
__global__ __launch_bounds__(256)
void softmax_mul_k(const float* __restrict__ s, float* __restrict__ A, int nb, int init)
{
    const long idx = (long)blockIdx.x * 256 + threadIdx.x;
    if (idx >= (long)nb * PX) return;
    const long b = idx >> 14, p = idx & 16383;
    const float* base = s + b * 10 * PX + p;
    float v[10]; float m = -1e30f;
#pragma unroll
    for (int t = 0; t < 10; t++) { v[t] = base[t * PX]; m = fmaxf(m, v[t]); }
    float sum = 0.f;
#pragma unroll
    for (int t = 0; t < 10; t++) { v[t] = expf(v[t] - m); sum += v[t]; }
    const float r = 1.f / sum;
    float* Ab = A + b * 10 * PX + p;
#pragma unroll
    for (int t = 0; t < 10; t++)
        Ab[t * PX] = init ? (v[t] * r) : (Ab[t * PX] * v[t] * r);
}

// ============ decoder attention score (y-part fused with cached Zpart) =====
__global__ __launch_bounds__(256)
void attn_fuse_k(const float* __restrict__ y, long ybs,
                 const float* __restrict__ zpart,      // [slot][b][32][PX]
                 const float* __restrict__ wt1,        // (32,129,3,3); y-ch = 0
                 const float* __restrict__ wt2, const float* __restrict__ bt2,
                 float* __restrict__ score, int nb)
{
    __shared__ float ylds[400];
    __shared__ float zl[32][324];
    const int tid = threadIdx.x;
    const int tileX = (blockIdx.x & 7) << 4, tileY = (blockIdx.x >> 3) << 4;
    const int z = blockIdx.z;
    const int b = z % nb, t = z / nb;

    for (int idx = tid; idx < 400; idx += 256) {
        const int r = idx / 20, c = idx - r * 20;
        const int gy = tileY + r - 2, gx = tileX + c - 2;
        ylds[idx] = ((unsigned)gy < 128u && (unsigned)gx < 128u)
                        ? y[(long)b * ybs + gy * 128 + gx] : 0.f;
    }
    __syncthreads();
    const float* zp0 = zpart + ((long)t * nb + b) * 32 * PX;
    for (int idx = tid; idx < 324; idx += 256) {
        const int zr = idx / 18, zc = idx - zr * 18;
        const int gy = tileY + zr - 1, gx = tileX + zc - 1;
        if ((unsigned)gy < 128u && (unsigned)gx < 128u) {
            float yw[9];
#pragma unroll
            for (int dy = 0; dy < 3; dy++)
#pragma unroll
                for (int dx = 0; dx < 3; dx++)
                    yw[dy * 3 + dx] = ylds[(zr + dy) * 20 + zc + dx];
            const long pix = (long)gy * 128 + gx;
#pragma unroll 8
            for (int ch = 0; ch < 32; ch++) {
                const float* wy = wt1 + (long)ch * 129 * 9;
                float s = zp0[(long)ch * PX + pix];
#pragma unroll
                for (int q = 0; q < 9; q++) s = fmaf(wy[q], yw[q], s);
                zl[ch][idx] = tanhf(s);
            }
        } else {
#pragma unroll 8
            for (int ch = 0; ch < 32; ch++) zl[ch][idx] = 0.f;
        }
    }
    __syncthreads();
    const int tx = tid & 15, ty = tid >> 4;
    float a = bt2[0];
    for (int ch = 0; ch < 32; ch++) {
#pragma unroll
        for (int ky = 0; ky < 3; ky++)
#pragma unroll
            for (int kx = 0; kx < 3; kx++)
                a = fmaf(wt2[ch * 9 + ky * 3 + kx], zl[ch][(ty + ky) * 18 + tx + kx], a);
    }
    score[((long)b * 10 + t) * PX + (long)(tileY + ty) * 128 + tileX + tx] = a;
}

// ============ fused softmax + temporal weighted sum, ch-group split ========
__global__ __launch_bounds__(256)
void smax_wsum_k(const float* __restrict__ score, const float* __restrict__ hs1,
                 float* __restrict__ aht, int nb)
{
    const long idx = (long)blockIdx.x * 256 + threadIdx.x;
    if (idx >= (long)nb * PX) return;
    const long b = idx >> 14, p = idx & 16383;
    const int ch0 = blockIdx.y * 8;
    const float* base = score + b * 10 * PX + p;
    float v[10]; float m = -1e30f;
#pragma unroll
    for (int t = 0; t < 10; t++) { v[t] = base[t * PX]; m = fmaxf(m, v[t]); }
    float sum = 0.f;
#pragma unroll
    for (int t = 0; t < 10; t++) { v[t] = expf(v[t] - m); sum += v[t]; }
    const float r = 1.f / sum;
#pragma unroll
    for (int t = 0; t < 10; t++) v[t] *= r;
    const long slot1 = (long)nb * 64 * PX;
#pragma unroll
    for (int j = 0; j < 8; j++) {
        const int ch = ch0 + j;
        float a = 0.f;
#pragma unroll
        for (int t = 0; t < 10; t++)
            a += v[t] * hs1[t * slot1 + (b * 64 + ch) * PX + p];
        aht[(b * 64 + ch) * PX + p] = a;
    }
}

// ---------------------------------------------------------------------------
extern "C" void kernel_launch(void* const* d_in, const int* in_sizes, int n_in,
                              void* d_out, int out_size, void* d_ws, size_t ws_size,
                              hipStream_t stream)
{
    const float* x      = (const float*)d_in[0];
    const float* h0     = (const float*)d_in[1];
    const float* c0in   = (const float*)d_in[2];
    const float* h1     = (const float*)d_in[3];
    const float* c1     = (const float*)d_in[4];
    const float* w_enc0 = (const float*)d_in[5];
    const float* b_enc0 = (const float*)d_in[6];
    const float* w_enc1 = (const float*)d_in[7];
    const float* b_enc1 = (const float*)d_in[8];
    const float* w_dec0 = (const float*)d_in[9];
    const float* b_dec0 = (const float*)d_in[10];
    const float* w_dec1 = (const float*)d_in[11];
    const float* b_dec1 = (const float*)d_in[12];
    const float* wa1 = (const float*)d_in[13];
    const float* ba1 = (const float*)d_in[14];
    const float* wa2 = (const float*)d_in[15];
    const float* ba2 = (const float*)d_in[16];
    const float* wt1 = (const float*)d_in[17];
    const float* bt1 = (const float*)d_in[18];
    const float* wt2 = (const float*)d_in[19];
    const float* bt2 = (const float*)d_in[20];
    float* out = (float*)d_out;

    // ---- adaptive batch tile for phase 2: need = (160 + 1188*nb)*PX*4 B ----
    int nb = 0;
    for (int cand = 8; cand >= 1; cand >>= 1) {
        const size_t need = (size_t)(160 + 1188 * cand) * PX * sizeof(float);
        if (need <= ws_size) { nb = cand; break; }
    }
    if (nb == 0) return;

    float* ws = (float*)d_ws;
    float* hs0 = ws;                      // [10][8][PX]
    float* cs0 = hs0 + 80 * PX;           // [10][8][PX]
    float* G   = cs0 + 80 * PX;
    // phase-1 aliases inside G
    float* A    = G;                      // [8][10][PX]
    float* sc1  = G + 80 * PX;            // [8][10][PX]
    float* pb0  = G + 160 * PX;           // [1][8][4][PX]
    // phase-2 per-group layout inside G
    const long slot1  = (long)nb * 64 * PX;          // hs1 per-t slot
    float* hs1   = G;                                 // 10 * slot1
    float* cs1   = hs1 + 10 * slot1;                  // 2 * slot1 (ping-pong)
    float* zpart = cs1 + 2 * slot1;                   // [10][nb][32][PX]
    float* aht   = zpart + (long)10 * nb * 32 * PX;   // [nb][64][PX]
    float* l1p   = aht + (long)nb * 64 * PX;          // [4][nb][4][PX]
    float* hs0g  = l1p + (long)4 * nb * 4 * PX;       // [5][nb][PX]
    float* cs0g  = hs0g + (long)5 * nb * PX;          // [5][nb][PX]
    float* scD   = cs0g + (long)5 * nb * PX;          // [nb][10][PX]

    const dim3 blk(256);
    const long TDP = (long)T_ * D_ * PX;
    const long zslot = (long)nb * 32 * PX;

    // ================= phase 1: encoder layer 0, FULL batch =================
    for (int t = 0; t < 10; t++) {
        const float* hprev = (t == 0) ? h0 : hs0 + (long)(t - 1) * 8 * PX;
        const float* cprev = (t == 0) ? c0in : cs0 + (long)(t - 1) * 8 * PX;
        iattn_k<<<dim3(64, 1, 80), blk, 0, stream>>>(
            x, A, hprev, cprev, wa1, ba1, wa2, ba2, sc1);
        softmax_mul_k<<<512, blk, 0, stream>>>(sc1, A, 8, t == 0);
        convp_k<4><<<dim3(64, 1, 8), blk, 0, stream>>>(
            x + (long)t * D_ * PX, 10, TDP, PX,
            hprev, PX, PX,
            A, 10 * PX, PX,
            w_enc0, 11, 0,
            make_int4(0, 0, 0, 0), make_int4(11, 0, 0, 0),
            pb0, 4, 8);
        combine_lstm_k<<<512, blk, 0, stream>>>(
            pb0, 1, 1, b_enc0, cprev, PX,
            hs0 + (long)t * 8 * PX, PX,
            cs0 + (long)t * 8 * PX, PX,
            (float*)nullptr, 0, 8);
    }

    // ================= phase 2: per batch-group =================
    for (int b0 = 0; b0 < 8; b0 += nb) {
        const float* xb  = x + (long)b0 * TDP;
        const float* h1b = h1 + (long)b0 * 64 * PX;
        const float* c1b = c1 + (long)b0 * 64 * PX;
        float* outb = out + (long)b0 * 5 * PX;

        // init all 10 zpart slots with bias (atomic targets)
        zfill_k<<<(int)(((long)10 * nb * 32 * PX + 255) / 256), blk, 0, stream>>>(
            zpart, bt1, (long)10 * nb * 32 * PX, 32);

        // -------- encoder layer 1 + incremental Zpart (atomic split-K) -----
        for (int t = 0; t < 10; t++) {
            const float* hprev = (t == 0) ? h1b : hs1 + (long)(t - 1) * slot1;
            const float* cprev = (t == 0) ? c1b : cs1 + (long)((t + 1) & 1) * slot1;
            conv_lstm_k<<<dim3(64, 32, nb), blk, 0, stream>>>(
                hs0 + (long)t * 8 * PX + (long)b0 * PX, 1, PX, PX,
                hprev, 64, 64 * PX, PX,
                w_enc1, b_enc1, 64, cprev, 64 * PX,
                hs1 + (long)t * slot1, 64 * PX,
                cs1 + (long)(t & 1) * slot1, 64 * PX);
            convp_at_k<<<dim3(64, 4, 4 * nb), blk, 0, stream>>>(
                hs1 + (long)t * slot1, 64, 64 * PX, PX,
                cs1 + (long)(t & 1) * slot1, 64 * PX, PX,
                wt1, 129, 1,
                make_int4(0, 32, 64, 96), make_int4(32, 32, 32, 32),
                zpart + (long)t * zslot, 32, nb);
        }

        // -------- decoder (5 steps) --------
        for (int s = 0; s < 5; s++) {
            const float* yptr; long ybs;
            if (s == 0) { yptr = xb + 9L * D_ * PX; ybs = TDP; }
            else        { yptr = hs0g + (long)(s - 1) * nb * PX; ybs = PX; }
            const float* hb1 = (s == 0) ? hs0 + 9L * 8 * PX + (long)b0 * PX
                                        : hs0g + (long)(s - 1) * nb * PX;
            const float* cb1 = (s == 0) ? cs0 + 9L * 8 * PX + (long)b0 * PX
                                        : cs0g + (long)(s - 1) * nb * PX;

            attn_fuse_k<<<dim3(64, 1, 10 * nb), blk, 0, stream>>>(
                yptr, ybs, zpart, wt1, wt2, bt2, scD, nb);
            smax_wsum_k<<<dim3((int)(((long)nb * PX + 255) / 256), 8), blk, 0, stream>>>(
                scD, hs1, aht, nb);

            // decoder LSTM 0: in = [y(1); aht(64)], c = cs1[(s+1)&1]
            conv_lstm_k<<<dim3(64, 32, nb), blk, 0, stream>>>(
                yptr, 1, ybs, PX, aht, 64, 64 * PX, PX,
                w_dec0, b_dec0, 64,
                cs1 + (long)((s + 1) & 1) * slot1, 64 * PX,
                hs1 + (long)s * slot1, 64 * PX,
                cs1 + (long)(s & 1) * slot1, 64 * PX);

            // decoder LSTM 1 (split-K): in = [ht(64); hb1(1)]
            convp_k<4><<<dim3(64, 1, 4 * nb), blk, 0, stream>>>(
                hs1 + (long)s * slot1, 64, 64 * PX, PX,
                hb1, PX, PX,
                nullptr, 0, 0,
                w_dec1, 65, 0,
                make_int4(0, 17, 33, 49), make_int4(17, 16, 16, 16),
                l1p, 4, nb);
            combine_lstm_k<<<(int)(((long)nb * PX + 255) / 256), blk, 0, stream>>>(
                l1p, 4, 1, b_dec1, cb1, PX,
                hs0g + (long)s * nb * PX, PX,
                cs0g + (long)s * nb * PX, PX,
                outb + (long)s * PX, 5 * PX, nb);

            // Zpart update for rewritten slot s (skip last step):
            // reset slot to bias (after attn_fuse consumed old values), then
            // atomic split-K add of the new h,c conv.
            if (s < 4) {
                zfill_k<<<(int)(((long)nb * 32 * PX + 255) / 256), blk, 0, stream>>>(
                    zpart + (long)s * zslot, bt1, (long)nb * 32 * PX, 32);
                convp_at_k<<<dim3(64, 4, 4 * nb), blk, 0, stream>>>(
                    hs1 + (long)s * slot1, 64, 64 * PX, PX,
                    cs1 + (long)(s & 1) * slot1, 64 * PX, PX,
                    wt1, 129, 1,
                    make_int4(0, 32, 64, 96), make_int4(32, 32, 32, 32),
                    zpart + (long)s * zslot, 32, nb);
            }
        }
    }
}

// Round 7
// 27429.425 us; speedup vs baseline: 1.1572x; 1.1572x over previous
//
#include <hip/hip_runtime.h>

// ---------------------------------------------------------------------------
// WeatherModel ConvLSTM enc-dec, fp32, MI355X. Round 7: dispatch-count attack.
// R6 post-mortem: 16x16 tiles + same-address split-K atomics regressed 22% ->
// revert to 32-wide tiles, no atomics. New: merge independent work into single
// dispatches (enc: conv_lstm(t) + zpart(t-1); dec: l1p-conv + zpart(s)), direct
// (non-split-K) zpart, direct phase-1 LSTM. 544 -> ~318 dispatches at nb=1.
// Also fixes latent t=0 bug: iattn read poisoned A; now A=nullptr => scale 1.
// ---------------------------------------------------------------------------

#define PX 16384L   // 128*128
#define T_ 10
#define D_ 10

__device__ __forceinline__ float sigmoidf_(float x) { return 1.f / (1.f + expf(-x)); }

// ============ device: fused conv3x3+LSTM gates, 32x16 tile, 2px/thread =====
// cin = 1 (in0) + 64 (in1, ch-stride PX, b-stride 64PX). hidden=64.
__device__ __forceinline__ void lstm_dev(
    float* lds,                        // 8*612 floats
    int tile, int hcb, int b,
    const float* __restrict__ in0, long bs0,
    const float* __restrict__ in1,
    const float* __restrict__ w, const float* __restrict__ bias,
    const float* __restrict__ cprev,
    float* __restrict__ hout, float* __restrict__ cout_)
{
    const int tid = threadIdx.x;
    const int tx = tid & 31, r0 = (tid >> 5) << 1;
    const int tileX = (tile & 3) << 5, tileY = (tile >> 2) << 4;
    const int hc0 = hcb << 1;
    float acc[16];                     // [hc2][g4][rr2]
#pragma unroll
    for (int j = 0; j < 16; j++) acc[j] = 0.f;

    for (int cb = 0; cb < 65; cb += 8) {
        const int cmax = min(8, 65 - cb);
        for (int cl = 0; cl < cmax; cl++) {
            const int ci = cb + cl;
            const float* p = (ci == 0) ? in0 + (long)b * bs0
                                       : in1 + ((long)b * 64 + (ci - 1)) * PX;
            for (int idx = tid; idx < 612; idx += 256) {
                const int r = idx / 34, cc = idx - r * 34;
                const int gy = tileY + r - 1, gx = tileX + cc - 1;
                lds[cl * 612 + idx] = ((unsigned)gy < 128u && (unsigned)gx < 128u)
                                          ? p[gy * 128 + gx] : 0.f;
            }
        }
        __syncthreads();
        for (int cl = 0; cl < cmax; cl++) {
            float win[4][3];
#pragma unroll
            for (int dy = 0; dy < 4; dy++)
#pragma unroll
                for (int dx = 0; dx < 3; dx++)
                    win[dy][dx] = lds[cl * 612 + (r0 + dy) * 34 + tx + dx];
            const int ci = cb + cl;
#pragma unroll
            for (int j = 0; j < 2; j++)
#pragma unroll
                for (int g = 0; g < 4; g++) {
                    const float* wp = w + ((long)(g * 64 + hc0 + j) * 65 + ci) * 9;
#pragma unroll
                    for (int rr = 0; rr < 2; rr++) {
                        float a = acc[(j * 4 + g) * 2 + rr];
#pragma unroll
                        for (int ky = 0; ky < 3; ky++)
#pragma unroll
                            for (int kx = 0; kx < 3; kx++)
                                a = fmaf(wp[ky * 3 + kx], win[rr + ky][kx], a);
                        acc[(j * 4 + g) * 2 + rr] = a;
                    }
                }
        }
        __syncthreads();
    }
#pragma unroll
    for (int j = 0; j < 2; j++) {
        const int hc = hc0 + j;
        const float bi = bias[hc], bf = bias[64 + hc];
        const float bo = bias[128 + hc], bg = bias[192 + hc];
#pragma unroll
        for (int rr = 0; rr < 2; rr++) {
            const long opix = (long)(tileY + r0 + rr) * 128 + tileX + tx;
            const float i_ = sigmoidf_(acc[(j * 4 + 0) * 2 + rr] + bi);
            const float f_ = sigmoidf_(acc[(j * 4 + 1) * 2 + rr] + bf);
            const float o_ = sigmoidf_(acc[(j * 4 + 2) * 2 + rr] + bo);
            const float g_ = tanhf(acc[(j * 4 + 3) * 2 + rr] + bg);
            const float cp = cprev[((long)b * 64 + hc) * PX + opix];
            const float c2 = f_ * cp + i_ * g_;
            const float h2 = o_ * tanhf(c2);
            hout[((long)b * 64 + hc) * PX + opix] = h2;
            cout_[((long)b * 64 + hc) * PX + opix] = c2;
        }
    }
}

// ============ device: direct zpart conv (128->32, skip y-ch 0 of wt1) ======
// 16x16 tile. zdst[b][32][PX] = conv(wt1[:,1:129], [h;c]) + bt1
__device__ __forceinline__ void zpart_dev(
    float* lds,                        // 4*324 floats
    int tile, int cob, int b,
    const float* __restrict__ hsrc, const float* __restrict__ csrc,
    const float* __restrict__ wt1, const float* __restrict__ bt1,
    float* __restrict__ zdst)
{
    const int tid = threadIdx.x;
    const int tx = tid & 15, ty = tid >> 4;
    const int tileX = (tile & 7) << 4, tileY = (tile >> 3) << 4;
    const int co0 = cob << 3;
    float acc[8];
#pragma unroll
    for (int j = 0; j < 8; j++) acc[j] = 0.f;

    for (int cb = 0; cb < 128; cb += 4) {
        for (int cl = 0; cl < 4; cl++) {
            const int ci = cb + cl;
            const float* p = (ci < 64) ? hsrc + ((long)b * 64 + ci) * PX
                                       : csrc + ((long)b * 64 + (ci - 64)) * PX;
            for (int idx = tid; idx < 324; idx += 256) {
                const int r = idx / 18, cc = idx - r * 18;
                const int gy = tileY + r - 1, gx = tileX + cc - 1;
                lds[cl * 324 + idx] = ((unsigned)gy < 128u && (unsigned)gx < 128u)
                                          ? p[gy * 128 + gx] : 0.f;
            }
        }
        __syncthreads();
        for (int cl = 0; cl < 4; cl++) {
            float r9[9];
#pragma unroll
            for (int dy = 0; dy < 3; dy++)
#pragma unroll
                for (int dx = 0; dx < 3; dx++)
                    r9[dy * 3 + dx] = lds[cl * 324 + (ty + dy) * 18 + tx + dx];
            const int ci = cb + cl;
#pragma unroll
            for (int j = 0; j < 8; j++) {
                const float* wp = wt1 + ((long)(co0 + j) * 129 + 1 + ci) * 9;
                float a = acc[j];
#pragma unroll
                for (int q = 0; q < 9; q++) a = fmaf(wp[q], r9[q], a);
                acc[j] = a;
            }
        }
        __syncthreads();
    }
    const long opix = (long)(tileY + ty) * 128 + tileX + tx;
#pragma unroll
    for (int j = 0; j < 8; j++)
        zdst[((long)b * 32 + co0 + j) * PX + opix] = acc[j] + bt1[co0 + j];
}

// ============ merged dispatch: conv_lstm (1024 blk) [+ zpart (256 blk)] ====
__global__ __launch_bounds__(256)
void lstm_merge_k(const float* __restrict__ in0, long bs0,
                  const float* __restrict__ in1,
                  const float* __restrict__ w, const float* __restrict__ bias,
                  const float* __restrict__ cprev,
                  float* __restrict__ hout, float* __restrict__ cout_,
                  const float* __restrict__ zh, const float* __restrict__ zc,
                  float* __restrict__ zdst,
                  const float* __restrict__ wt1, const float* __restrict__ bt1)
{
    __shared__ float lds[8 * 612];
    const int bid = blockIdx.x, b = blockIdx.z;
    if (bid < 1024) {
        lstm_dev(lds, bid & 31, bid >> 5, b, in0, bs0, in1, w, bias,
                 cprev, hout, cout_);
    } else {
        const int q = bid - 1024;
        zpart_dev(lds, q & 63, q >> 6, b, zh, zc, wt1, bt1, zdst);
    }
}

// ============ standalone zpart (t=9) =======================================
__global__ __launch_bounds__(256)
void zpart_k(const float* __restrict__ zh, const float* __restrict__ zc,
             float* __restrict__ zdst,
             const float* __restrict__ wt1, const float* __restrict__ bt1)
{
    __shared__ float lds[4 * 324];
    zpart_dev(lds, blockIdx.x, blockIdx.y, blockIdx.z, zh, zc, wt1, bt1, zdst);
}

// ============ merged dispatch: dec-LSTM1 split-K conv [+ zpart(s)] =========
__global__ __launch_bounds__(256)
void dec_merge_k(const float* __restrict__ hs1s,
                 const float* __restrict__ hb1, long hb1bs,
                 const float* __restrict__ w1,          // (4,65,3,3)
                 float* __restrict__ l1p, int nb,
                 const float* __restrict__ zc, float* __restrict__ zdst,
                 const float* __restrict__ wt1, const float* __restrict__ bt1)
{
    __shared__ float lds[4 * 324];
    const int bid = blockIdx.x, b = blockIdx.z;
    if (bid < 256) {
        const int tile = bid & 63, s = bid >> 6;
        const int ci0 = (s == 0) ? 0 : (s == 1) ? 17 : (s == 2) ? 33 : 49;
        const int cn  = (s == 0) ? 17 : 16;
        const int tid = threadIdx.x;
        const int tx = tid & 15, ty = tid >> 4;
        const int tileX = (tile & 7) << 4, tileY = (tile >> 3) << 4;
        float acc[4] = {0.f, 0.f, 0.f, 0.f};
        for (int cb = 0; cb < cn; cb += 4) {
            const int cmax = min(4, cn - cb);
            for (int cl = 0; cl < cmax; cl++) {
                const int ci = ci0 + cb + cl;
                const float* p = (ci < 64) ? hs1s + ((long)b * 64 + ci) * PX
                                           : hb1 + (long)b * hb1bs;
                for (int idx = tid; idx < 324; idx += 256) {
                    const int r = idx / 18, cc = idx - r * 18;
                    const int gy = tileY + r - 1, gx = tileX + cc - 1;
                    lds[cl * 324 + idx] = ((unsigned)gy < 128u && (unsigned)gx < 128u)
                                              ? p[gy * 128 + gx] : 0.f;
                }
            }
            __syncthreads();
            for (int cl = 0; cl < cmax; cl++) {
                float r9[9];
#pragma unroll
                for (int dy = 0; dy < 3; dy++)
#pragma unroll
                    for (int dx = 0; dx < 3; dx++)
                        r9[dy * 3 + dx] = lds[cl * 324 + (ty + dy) * 18 + tx + dx];
                const int ci = ci0 + cb + cl;
#pragma unroll
                for (int j = 0; j < 4; j++) {
                    const float* wp = w1 + ((long)j * 65 + ci) * 9;
                    float a = acc[j];
#pragma unroll
                    for (int q = 0; q < 9; q++) a = fmaf(wp[q], r9[q], a);
                    acc[j] = a;
                }
            }
            __syncthreads();
        }
        const long opix = (long)(tileY + ty) * 128 + tileX + tx;
#pragma unroll
        for (int j = 0; j < 4; j++)
            l1p[(((long)s * nb + b) * 4 + j) * PX + opix] = acc[j];
    } else {
        const int q = bid - 256;
        zpart_dev(lds, q & 63, q >> 6, b, hs1s, zc, wt1, bt1, zdst);
    }
}

// ============ combine split-K LSTM gate partials -> h,c,out2 ===============
__global__ __launch_bounds__(256)
void combine_lstm_k(const float* __restrict__ pbuf, int nsl, int hidden,
                    const float* __restrict__ bias,
                    const float* __restrict__ cprev, long cpbs,
                    float* __restrict__ hout, long hobs,
                    float* __restrict__ cout_, long cobs,
                    float* __restrict__ hout2, long ho2bs, int nb)
{
    const long idx = (long)blockIdx.x * 256 + threadIdx.x;
    if (idx >= (long)nb * hidden * PX) return;
    const long px = idx & 16383;
    const long v = idx >> 14;
    const int hc = (int)(v % hidden), b = (int)(v / hidden);
    const int nco = 4 * hidden;
    float g4[4] = {0.f, 0.f, 0.f, 0.f};
    for (int s = 0; s < nsl; s++)
#pragma unroll
        for (int g = 0; g < 4; g++)
            g4[g] += pbuf[(((long)s * nb + b) * nco + g * hidden + hc) * PX + px];
    const float i_ = sigmoidf_(g4[0] + bias[hc]);
    const float f_ = sigmoidf_(g4[1] + bias[hidden + hc]);
    const float o_ = sigmoidf_(g4[2] + bias[2 * hidden + hc]);
    const float g_ = tanhf(g4[3] + bias[3 * hidden + hc]);
    const float cp = cprev[(long)b * cpbs + (long)hc * PX + px];
    const float c2 = f_ * cp + i_ * g_;
    const float h2 = o_ * tanhf(c2);
    hout[(long)b * hobs + (long)hc * PX + px] = h2;
    cout_[(long)b * cobs + (long)hc * PX + px] = c2;
    if (hout2) hout2[(long)b * ho2bs + (long)hc * PX + px] = h2;
}

// ============ phase-1 enc0 LSTM: direct fused conv (11 ch) + gates =========
__global__ __launch_bounds__(256)
void enc0_lstm_k(const float* __restrict__ x, int t, const float* __restrict__ A,
                 const float* __restrict__ hprev, const float* __restrict__ cprev,
                 const float* __restrict__ w, const float* __restrict__ bias,
                 float* __restrict__ hout, float* __restrict__ cout_)
{
    __shared__ float lds[4 * 324];
    const int tid = threadIdx.x;
    const int tx = tid & 15, ty = tid >> 4;
    const int tile = blockIdx.x, b = blockIdx.z;
    const int tileX = (tile & 7) << 4, tileY = (tile >> 3) << 4;
    float acc[4] = {0.f, 0.f, 0.f, 0.f};
    for (int cb = 0; cb < 11; cb += 4) {
        const int cmax = min(4, 11 - cb);
        for (int cl = 0; cl < cmax; cl++) {
            const int ci = cb + cl;
            const float* p; const float* sp = nullptr;
            if (ci < 10) {
                p = x + (((long)b * T_ + t) * D_ + ci) * PX;
                sp = A + ((long)b * 10 + ci) * PX;
            } else {
                p = hprev + (long)b * PX;
            }
            for (int idx = tid; idx < 324; idx += 256) {
                const int r = idx / 18, cc = idx - r * 18;
                const int gy = tileY + r - 1, gx = tileX + cc - 1;
                float v = 0.f;
                if ((unsigned)gy < 128u && (unsigned)gx < 128u) {
                    v = p[gy * 128 + gx];
                    if (sp) v *= sp[gy * 128 + gx];
                }
                lds[cl * 324 + idx] = v;
            }
        }
        __syncthreads();
        for (int cl = 0; cl < cmax; cl++) {
            float r9[9];
#pragma unroll
            for (int dy = 0; dy < 3; dy++)
#pragma unroll
                for (int dx = 0; dx < 3; dx++)
                    r9[dy * 3 + dx] = lds[cl * 324 + (ty + dy) * 18 + tx + dx];
            const int ci = cb + cl;
#pragma unroll
            for (int g = 0; g < 4; g++) {
                const float* wp = w + ((long)g * 11 + ci) * 9;
                float a = acc[g];
#pragma unroll
                for (int q = 0; q < 9; q++) a = fmaf(wp[q], r9[q], a);
                acc[g] = a;
            }
        }
        __syncthreads();
    }
    const long opix = (long)(tileY + ty) * 128 + tileX + tx;
    const float i_ = sigmoidf_(acc[0] + bias[0]);
    const float f_ = sigmoidf_(acc[1] + bias[1]);
    const float o_ = sigmoidf_(acc[2] + bias[2]);
    const float g_ = tanhf(acc[3] + bias[3]);
    const float cp = cprev[(long)b * PX + opix];
    const float c2 = f_ * cp + i_ * g_;
    const float h2 = o_ * tanhf(c2);
    hout[(long)b * PX + opix] = h2;
    cout_[(long)b * PX + opix] = c2;
}

// ============ fused input-attention score (phase 1, full batch) ============
// A == nullptr => scale 1 (t=0: reference uses unscaled x).
__global__ __launch_bounds__(256)
void iattn_k(const float* __restrict__ x, const float* __restrict__ A,
             const float* __restrict__ h, const float* __restrict__ c,
             const float* __restrict__ wa1, const float* __restrict__ ba1,
             const float* __restrict__ wa2, const float* __restrict__ ba2,
             float* __restrict__ score)
{
    __shared__ float xl[12][400];
    __shared__ float zl[32][324];
    const int tid = threadIdx.x;
    const int tileX = (blockIdx.x & 7) << 4, tileY = (blockIdx.x >> 3) << 4;
    const int z = blockIdx.z;
    const int b = z & 7, k = z >> 3;

    float* aT = &zl[0][0];
    for (int idx = tid; idx < 400; idx += 256) {
        const int r = idx / 20, cc = idx - r * 20;
        const int gy = tileY + r - 2, gx = tileX + cc - 2;
        aT[idx] = (A && (unsigned)gy < 128u && (unsigned)gx < 128u)
                      ? A[((long)b * 10 + k) * PX + gy * 128 + gx]
                      : (A ? 0.f : 1.f);
    }
    __syncthreads();
    for (int ch = 0; ch < 12; ch++) {
        const float* p = (ch < 10) ? x + (((long)b * 10 + ch) * 10 + k) * PX
                       : (ch == 10) ? h + (long)b * PX : c + (long)b * PX;
        for (int idx = tid; idx < 400; idx += 256) {
            const int r = idx / 20, cc = idx - r * 20;
            const int gy = tileY + r - 2, gx = tileX + cc - 2;
            float v = 0.f;
            if ((unsigned)gy < 128u && (unsigned)gx < 128u) {
                v = p[gy * 128 + gx];
                if (ch < 10) v *= aT[idx];
            }
            xl[ch][idx] = v;
        }
    }
    __syncthreads();
    const int i0 = tid, i1 = tid + 256;
    const int zr0 = i0 / 18, zc0 = i0 - zr0 * 18;
    const int zr1 = (i1 < 324) ? i1 / 18 : 0, zc1 = (i1 < 324) ? i1 - (i1 / 18) * 18 : 0;
    float acc0[32], acc1[32];
#pragma unroll
    for (int co = 0; co < 32; co++) { acc0[co] = 0.f; acc1[co] = 0.f; }
    for (int ci = 0; ci < 12; ci++) {
        float wA[9], wB[9];
#pragma unroll
        for (int dy = 0; dy < 3; dy++)
#pragma unroll
            for (int dx = 0; dx < 3; dx++) {
                wA[dy * 3 + dx] = xl[ci][(zr0 + dy) * 20 + zc0 + dx];
                wB[dy * 3 + dx] = xl[ci][(zr1 + dy) * 20 + zc1 + dx];
            }
#pragma unroll
        for (int co = 0; co < 32; co++) {
            const float* wp = wa1 + ((long)co * 12 + ci) * 9;
            float a0 = acc0[co], a1 = acc1[co];
#pragma unroll
            for (int q = 0; q < 9; q++) { a0 = fmaf(wp[q], wA[q], a0); a1 = fmaf(wp[q], wB[q], a1); }
            acc0[co] = a0; acc1[co] = a1;
        }
    }
    __syncthreads();
    {
        const int gy0 = tileY + zr0 - 1, gx0 = tileX + zc0 - 1;
        const bool in0_ = ((unsigned)gy0 < 128u && (unsigned)gx0 < 128u);
        const int gy1 = tileY + zr1 - 1, gx1 = tileX + zc1 - 1;
        const bool in1_ = (i1 < 324) && ((unsigned)gy1 < 128u && (unsigned)gx1 < 128u);
#pragma unroll
        for (int co = 0; co < 32; co++) {
            zl[co][i0] = in0_ ? tanhf(acc0[co] + ba1[co]) : 0.f;
            if (i1 < 324) zl[co][i1] = in1_ ? tanhf(acc1[co] + ba1[co]) : 0.f;
        }
    }
    __syncthreads();
    const int tx = tid & 15, ty = tid >> 4;
    float a = ba2[0];
    for (int co = 0; co < 32; co++) {
#pragma unroll
        for (int ky = 0; ky < 3; ky++)
#pragma unroll
            for (int kx = 0; kx < 3; kx++)
                a = fmaf(wa2[co * 9 + ky * 3 + kx], zl[co][(ty + ky) * 18 + tx + kx], a);
    }
    score[((long)b * 10 + k) * PX + (long)(tileY + ty) * 128 + tileX + tx] = a;
}

// ============ softmax over 10 (+compound into A) ===========================
__global__ __launch_bounds__(256)
void softmax_mul_k(const float* __restrict__ s, float* __restrict__ A, int nb, int init)
{
    const long idx = (long)blockIdx.x * 256 + threadIdx.x;
    if (idx >= (long)nb * PX) return;
    const long b = idx >> 14, p = idx & 16383;
    const float* base = s + b * 10 * PX + p;
    float v[10]; float m = -1e30f;
#pragma unroll
    for (int t = 0; t < 10; t++) { v[t] = base[t * PX]; m = fmaxf(m, v[t]); }
    float sum = 0.f;
#pragma unroll
    for (int t = 0; t < 10; t++) { v[t] = expf(v[t] - m); sum += v[t]; }
    const float r = 1.f / sum;
    float* Ab = A + b * 10 * PX + p;
#pragma unroll
    for (int t = 0; t < 10; t++)
        Ab[t * PX] = init ? (v[t] * r) : (Ab[t * PX] * v[t] * r);
}

// ============ decoder attention score (y-part fused with cached Zpart) =====
__global__ __launch_bounds__(256)
void attn_fuse_k(const float* __restrict__ y, long ybs,
                 const float* __restrict__ zpart,
                 const float* __restrict__ wt1,
                 const float* __restrict__ wt2, const float* __restrict__ bt2,
                 float* __restrict__ score, int nb)
{
    __shared__ float ylds[400];
    __shared__ float zl[32][324];
    const int tid = threadIdx.x;
    const int tileX = (blockIdx.x & 7) << 4, tileY = (blockIdx.x >> 3) << 4;
    const int z = blockIdx.z;
    const int b = z % nb, t = z / nb;

    for (int idx = tid; idx < 400; idx += 256) {
        const int r = idx / 20, c = idx - r * 20;
        const int gy = tileY + r - 2, gx = tileX + c - 2;
        ylds[idx] = ((unsigned)gy < 128u && (unsigned)gx < 128u)
                        ? y[(long)b * ybs + gy * 128 + gx] : 0.f;
    }
    __syncthreads();
    const float* zp0 = zpart + ((long)t * nb + b) * 32 * PX;
    for (int idx = tid; idx < 324; idx += 256) {
        const int zr = idx / 18, zc = idx - zr * 18;
        const int gy = tileY + zr - 1, gx = tileX + zc - 1;
        if ((unsigned)gy < 128u && (unsigned)gx < 128u) {
            float yw[9];
#pragma unroll
            for (int dy = 0; dy < 3; dy++)
#pragma unroll
                for (int dx = 0; dx < 3; dx++)
                    yw[dy * 3 + dx] = ylds[(zr + dy) * 20 + zc + dx];
            const long pix = (long)gy * 128 + gx;
#pragma unroll 8
            for (int ch = 0; ch < 32; ch++) {
                const float* wy = wt1 + (long)ch * 129 * 9;
                float s = zp0[(long)ch * PX + pix];
#pragma unroll
                for (int q = 0; q < 9; q++) s = fmaf(wy[q], yw[q], s);
                zl[ch][idx] = tanhf(s);
            }
        } else {
#pragma unroll 8
            for (int ch = 0; ch < 32; ch++) zl[ch][idx] = 0.f;
        }
    }
    __syncthreads();
    const int tx = tid & 15, ty = tid >> 4;
    float a = bt2[0];
    for (int ch = 0; ch < 32; ch++) {
#pragma unroll
        for (int ky = 0; ky < 3; ky++)
#pragma unroll
            for (int kx = 0; kx < 3; kx++)
                a = fmaf(wt2[ch * 9 + ky * 3 + kx], zl[ch][(ty + ky) * 18 + tx + kx], a);
    }
    score[((long)b * 10 + t) * PX + (long)(tileY + ty) * 128 + tileX + tx] = a;
}

// ============ fused softmax + temporal weighted sum, ch-group split ========
__global__ __launch_bounds__(256)
void smax_wsum_k(const float* __restrict__ score, const float* __restrict__ hs1,
                 float* __restrict__ aht, int nb)
{
    const long idx = (long)blockIdx.x * 256 + threadIdx.x;
    if (idx >= (long)nb * PX) return;
    const long b = idx >> 14, p = idx & 16383;
    const int ch0 = blockIdx.y * 8;
    const float* base = score + b * 10 * PX + p;
    float v[10]; float m = -1e30f;
#pragma unroll
    for (int t = 0; t < 10; t++) { v[t] = base[t * PX]; m = fmaxf(m, v[t]); }
    float sum = 0.f;
#pragma unroll
    for (int t = 0; t < 10; t++) { v[t] = expf(v[t] - m); sum += v[t]; }
    const float r = 1.f / sum;
#pragma unroll
    for (int t = 0; t < 10; t++) v[t] *= r;
    const long slot1 = (long)nb * 64 * PX;
#pragma unroll
    for (int j = 0; j < 8; j++) {
        const int ch = ch0 + j;
        float a = 0.f;
#pragma unroll
        for (int t = 0; t < 10; t++)
            a += v[t] * hs1[t * slot1 + (b * 64 + ch) * PX + p];
        aht[(b * 64 + ch) * PX + p] = a;
    }
}

// ---------------------------------------------------------------------------
extern "C" void kernel_launch(void* const* d_in, const int* in_sizes, int n_in,
                              void* d_out, int out_size, void* d_ws, size_t ws_size,
                              hipStream_t stream)
{
    const float* x      = (const float*)d_in[0];
    const float* h0     = (const float*)d_in[1];
    const float* c0in   = (const float*)d_in[2];
    const float* h1     = (const float*)d_in[3];
    const float* c1     = (const float*)d_in[4];
    const float* w_enc0 = (const float*)d_in[5];
    const float* b_enc0 = (const float*)d_in[6];
    const float* w_enc1 = (const float*)d_in[7];
    const float* b_enc1 = (const float*)d_in[8];
    const float* w_dec0 = (const float*)d_in[9];
    const float* b_dec0 = (const float*)d_in[10];
    const float* w_dec1 = (const float*)d_in[11];
    const float* b_dec1 = (const float*)d_in[12];
    const float* wa1 = (const float*)d_in[13];
    const float* ba1 = (const float*)d_in[14];
    const float* wa2 = (const float*)d_in[15];
    const float* ba2 = (const float*)d_in[16];
    const float* wt1 = (const float*)d_in[17];
    const float* bt1 = (const float*)d_in[18];
    const float* wt2 = (const float*)d_in[19];
    const float* bt2 = (const float*)d_in[20];
    float* out = (float*)d_out;

    // ---- adaptive batch tile: need = (160 + 1188*nb)*PX*4 B ----
    int nb = 0;
    for (int cand = 8; cand >= 1; cand >>= 1) {
        const size_t need = (size_t)(160 + 1188 * cand) * PX * sizeof(float);
        if (need <= ws_size) { nb = cand; break; }
    }
    if (nb == 0) return;

    float* ws = (float*)d_ws;
    float* hs0 = ws;                      // [10][8][PX]
    float* cs0 = hs0 + 80 * PX;           // [10][8][PX]
    float* G   = cs0 + 80 * PX;
    // phase-1 aliases inside G
    float* A    = G;                      // [8][10][PX]
    float* sc1  = G + 80 * PX;            // [8][10][PX]
    // phase-2 per-group layout inside G
    const long slot1  = (long)nb * 64 * PX;
    float* hs1   = G;                                 // 10 * slot1
    float* cs1   = hs1 + 10 * slot1;                  // 2 * slot1 (ping-pong)
    float* zpart = cs1 + 2 * slot1;                   // [10][nb][32][PX]
    float* aht   = zpart + (long)10 * nb * 32 * PX;   // [nb][64][PX]
    float* l1p   = aht + (long)nb * 64 * PX;          // [4][nb][4][PX]
    float* hs0g  = l1p + (long)4 * nb * 4 * PX;       // [5][nb][PX]
    float* cs0g  = hs0g + (long)5 * nb * PX;          // [5][nb][PX]
    float* scD   = cs0g + (long)5 * nb * PX;          // [nb][10][PX]

    const dim3 blk(256);
    const long TDP = (long)T_ * D_ * PX;
    const long zslot = (long)nb * 32 * PX;

    // ================= phase 1: encoder layer 0, FULL batch =================
    for (int t = 0; t < 10; t++) {
        const float* hprev = (t == 0) ? h0 : hs0 + (long)(t - 1) * 8 * PX;
        const float* cprev = (t == 0) ? c0in : cs0 + (long)(t - 1) * 8 * PX;
        iattn_k<<<dim3(64, 1, 80), blk, 0, stream>>>(
            x, (t == 0) ? nullptr : A, hprev, cprev, wa1, ba1, wa2, ba2, sc1);
        softmax_mul_k<<<512, blk, 0, stream>>>(sc1, A, 8, t == 0);
        enc0_lstm_k<<<dim3(64, 1, 8), blk, 0, stream>>>(
            x, t, A, hprev, cprev, w_enc0, b_enc0,
            hs0 + (long)t * 8 * PX, cs0 + (long)t * 8 * PX);
    }

    // ================= phase 2: per batch-group =================
    for (int b0 = 0; b0 < 8; b0 += nb) {
        const float* xb  = x + (long)b0 * TDP;
        float* outb = out + (long)b0 * 5 * PX;

        // -------- encoder layer 1, with zpart(t-1) merged in ---------------
        for (int t = 0; t < 10; t++) {
            const float* hprev = (t == 0) ? h1 + (long)b0 * 64 * PX
                                          : hs1 + (long)(t - 1) * slot1;
            const float* cprev = (t == 0) ? c1 + (long)b0 * 64 * PX
                                          : cs1 + (long)((t - 1) & 1) * slot1;
            const int gx = (t == 0) ? 1024 : 1280;
            lstm_merge_k<<<dim3(gx, 1, nb), blk, 0, stream>>>(
                hs0 + (long)t * 8 * PX + (long)b0 * PX, PX,
                hprev, w_enc1, b_enc1, cprev,
                hs1 + (long)t * slot1, cs1 + (long)(t & 1) * slot1,
                (t == 0) ? nullptr : hs1 + (long)(t - 1) * slot1,
                (t == 0) ? nullptr : cs1 + (long)((t - 1) & 1) * slot1,
                (t == 0) ? nullptr : zpart + (long)(t - 1) * zslot,
                wt1, bt1);
        }
        zpart_k<<<dim3(64, 4, nb), blk, 0, stream>>>(
            hs1 + 9L * slot1, cs1 + slot1, zpart + 9L * zslot, wt1, bt1);

        // -------- decoder (5 steps) --------
        for (int s = 0; s < 5; s++) {
            const float* yptr; long ybs;
            if (s == 0) { yptr = xb + 9L * D_ * PX; ybs = TDP; }
            else        { yptr = hs0g + (long)(s - 1) * nb * PX; ybs = PX; }
            const float* hb1 = (s == 0) ? hs0 + 9L * 8 * PX + (long)b0 * PX
                                        : hs0g + (long)(s - 1) * nb * PX;
            const float* cb1 = (s == 0) ? cs0 + 9L * 8 * PX + (long)b0 * PX
                                        : cs0g + (long)(s - 1) * nb * PX;

            attn_fuse_k<<<dim3(64, 1, 10 * nb), blk, 0, stream>>>(
                yptr, ybs, zpart, wt1, wt2, bt2, scD, nb);
            smax_wsum_k<<<dim3((int)(((long)nb * PX + 255) / 256), 8), blk, 0, stream>>>(
                scD, hs1, aht, nb);

            // decoder LSTM 0 (no merged zpart: it depends on this kernel)
            lstm_merge_k<<<dim3(1024, 1, nb), blk, 0, stream>>>(
                yptr, ybs, aht, w_dec0, b_dec0,
                cs1 + (long)((s + 1) & 1) * slot1,
                hs1 + (long)s * slot1, cs1 + (long)(s & 1) * slot1,
                nullptr, nullptr, nullptr, wt1, bt1);

            // dec LSTM1 split-K conv + zpart(s) (skip zpart at s=4)
            const int gx2 = (s < 4) ? 512 : 256;
            dec_merge_k<<<dim3(gx2, 1, nb), blk, 0, stream>>>(
                hs1 + (long)s * slot1, hb1, PX, w_dec1, l1p, nb,
                cs1 + (long)(s & 1) * slot1, zpart + (long)s * zslot, wt1, bt1);
            combine_lstm_k<<<(int)(((long)nb * PX + 255) / 256), blk, 0, stream>>>(
                l1p, 4, 1, b_dec1, cb1, PX,
                hs0g + (long)s * nb * PX, PX,
                cs0g + (long)s * nb * PX, PX,
                outb + (long)s * PX, 5 * PX, nb);
        }
    }
}

// Round 8
// 21857.924 us; speedup vs baseline: 1.4522x; 1.2549x over previous
//
#include <hip/hip_runtime.h>

// ---------------------------------------------------------------------------
// WeatherModel ConvLSTM enc-dec, fp32, MI355X. Round 8: counter-driven fixes.
// R7 rocprof: iattn_k 612us x10, LDS 60.9KB -> 23% occupancy, VALUBusy 58%;
// Dispatch_Id spacing => nb=2 tier is running. Fixes: (1) hoist staging
// address math out of channel loops (was ~46% VALU tax in lstm_merge);
// (2) fast tanh/sigmoid via v_exp+v_rcp (~5 instr vs ~25 libm); (3) iattn &
// attn_fuse co-halving: LDS 60.9->39.9KB / 43->22.3KB -> 2x-3x occupancy.
// Structure/launcher identical to R7.
// ---------------------------------------------------------------------------

#define PX 16384L   // 128*128
#define T_ 10
#define D_ 10

__device__ __forceinline__ float fast_tanh(float x) {
    const float e = __builtin_exp2f(x * 2.88539008f);          // e^{2x}
    return 1.f - 2.f * __builtin_amdgcn_rcpf(e + 1.f);
}
__device__ __forceinline__ float fast_sig(float x) {
    const float e = __builtin_exp2f(x * -1.44269504f);         // e^{-x}
    return __builtin_amdgcn_rcpf(e + 1.f);
}
__device__ __forceinline__ float fast_exp(float x) {
    return __builtin_exp2f(x * 1.44269504f);
}

// ============ device: fused conv3x3+LSTM gates, 32x16 tile, 2px/thread =====
// cin = 1 (in0) + 64 (in1, ch-stride PX, b-stride 64PX). hidden=64.
__device__ __forceinline__ void lstm_dev(
    float* lds,                        // 8*612 floats
    int tile, int hcb, int b,
    const float* __restrict__ in0, long bs0,
    const float* __restrict__ in1,
    const float* __restrict__ w, const float* __restrict__ bias,
    const float* __restrict__ cprev,
    float* __restrict__ hout, float* __restrict__ cout_)
{
    const int tid = threadIdx.x;
    const int tx = tid & 31, r0 = (tid >> 5) << 1;
    const int tileX = (tile & 3) << 5, tileY = (tile >> 2) << 4;
    const int hc0 = hcb << 1;
    float acc[16];                     // [hc2][g4][rr2]
#pragma unroll
    for (int j = 0; j < 16; j++) acc[j] = 0.f;

    // hoisted staging geometry (same for every channel)
    int g0[3]; float m0[3];
#pragma unroll
    for (int i = 0; i < 3; i++) {
        const int lidx = tid + i * 256;
        const int r = lidx / 34, cc = lidx - r * 34;
        const int gy = tileY + r - 1, gx = tileX + cc - 1;
        const bool inb = (lidx < 612) && ((unsigned)gy < 128u) && ((unsigned)gx < 128u);
        g0[i] = inb ? gy * 128 + gx : 0;
        m0[i] = inb ? 1.f : 0.f;
    }

    for (int cb = 0; cb < 65; cb += 8) {
        const int cmax = min(8, 65 - cb);
        for (int cl = 0; cl < cmax; cl++) {
            const int ci = cb + cl;
            const float* p = (ci == 0) ? in0 + (long)b * bs0
                                       : in1 + ((long)b * 64 + (ci - 1)) * PX;
#pragma unroll
            for (int i = 0; i < 3; i++) {
                const int lidx = tid + i * 256;
                if (lidx < 612) lds[cl * 612 + lidx] = m0[i] * p[g0[i]];
            }
        }
        __syncthreads();
        for (int cl = 0; cl < cmax; cl++) {
            float win[4][3];
#pragma unroll
            for (int dy = 0; dy < 4; dy++)
#pragma unroll
                for (int dx = 0; dx < 3; dx++)
                    win[dy][dx] = lds[cl * 612 + (r0 + dy) * 34 + tx + dx];
            const int ci = cb + cl;
#pragma unroll
            for (int j = 0; j < 2; j++)
#pragma unroll
                for (int g = 0; g < 4; g++) {
                    const float* wp = w + ((long)(g * 64 + hc0 + j) * 65 + ci) * 9;
#pragma unroll
                    for (int rr = 0; rr < 2; rr++) {
                        float a = acc[(j * 4 + g) * 2 + rr];
#pragma unroll
                        for (int ky = 0; ky < 3; ky++)
#pragma unroll
                            for (int kx = 0; kx < 3; kx++)
                                a = fmaf(wp[ky * 3 + kx], win[rr + ky][kx], a);
                        acc[(j * 4 + g) * 2 + rr] = a;
                    }
                }
        }
        __syncthreads();
    }
#pragma unroll
    for (int j = 0; j < 2; j++) {
        const int hc = hc0 + j;
        const float bi = bias[hc], bf = bias[64 + hc];
        const float bo = bias[128 + hc], bg = bias[192 + hc];
#pragma unroll
        for (int rr = 0; rr < 2; rr++) {
            const long opix = (long)(tileY + r0 + rr) * 128 + tileX + tx;
            const float i_ = fast_sig(acc[(j * 4 + 0) * 2 + rr] + bi);
            const float f_ = fast_sig(acc[(j * 4 + 1) * 2 + rr] + bf);
            const float o_ = fast_sig(acc[(j * 4 + 2) * 2 + rr] + bo);
            const float g_ = fast_tanh(acc[(j * 4 + 3) * 2 + rr] + bg);
            const float cp = cprev[((long)b * 64 + hc) * PX + opix];
            const float c2 = f_ * cp + i_ * g_;
            const float h2 = o_ * fast_tanh(c2);
            hout[((long)b * 64 + hc) * PX + opix] = h2;
            cout_[((long)b * 64 + hc) * PX + opix] = c2;
        }
    }
}

// ============ device: direct zpart conv (128->32, skip y-ch 0 of wt1) ======
__device__ __forceinline__ void zpart_dev(
    float* lds,                        // 4*324 floats
    int tile, int cob, int b,
    const float* __restrict__ hsrc, const float* __restrict__ csrc,
    const float* __restrict__ wt1, const float* __restrict__ bt1,
    float* __restrict__ zdst)
{
    const int tid = threadIdx.x;
    const int tx = tid & 15, ty = tid >> 4;
    const int tileX = (tile & 7) << 4, tileY = (tile >> 3) << 4;
    const int co0 = cob << 3;
    float acc[8];
#pragma unroll
    for (int j = 0; j < 8; j++) acc[j] = 0.f;

    int g0[2]; float m0[2];
#pragma unroll
    for (int i = 0; i < 2; i++) {
        const int lidx = tid + i * 256;
        const int r = lidx / 18, cc = lidx - r * 18;
        const int gy = tileY + r - 1, gx = tileX + cc - 1;
        const bool inb = (lidx < 324) && ((unsigned)gy < 128u) && ((unsigned)gx < 128u);
        g0[i] = inb ? gy * 128 + gx : 0;
        m0[i] = inb ? 1.f : 0.f;
    }

    for (int cb = 0; cb < 128; cb += 4) {
        for (int cl = 0; cl < 4; cl++) {
            const int ci = cb + cl;
            const float* p = (ci < 64) ? hsrc + ((long)b * 64 + ci) * PX
                                       : csrc + ((long)b * 64 + (ci - 64)) * PX;
#pragma unroll
            for (int i = 0; i < 2; i++) {
                const int lidx = tid + i * 256;
                if (lidx < 324) lds[cl * 324 + lidx] = m0[i] * p[g0[i]];
            }
        }
        __syncthreads();
        for (int cl = 0; cl < 4; cl++) {
            float r9[9];
#pragma unroll
            for (int dy = 0; dy < 3; dy++)
#pragma unroll
                for (int dx = 0; dx < 3; dx++)
                    r9[dy * 3 + dx] = lds[cl * 324 + (ty + dy) * 18 + tx + dx];
            const int ci = cb + cl;
#pragma unroll
            for (int j = 0; j < 8; j++) {
                const float* wp = wt1 + ((long)(co0 + j) * 129 + 1 + ci) * 9;
                float a = acc[j];
#pragma unroll
                for (int q = 0; q < 9; q++) a = fmaf(wp[q], r9[q], a);
                acc[j] = a;
            }
        }
        __syncthreads();
    }
    const long opix = (long)(tileY + ty) * 128 + tileX + tx;
#pragma unroll
    for (int j = 0; j < 8; j++)
        zdst[((long)b * 32 + co0 + j) * PX + opix] = acc[j] + bt1[co0 + j];
}

// ============ merged dispatch: conv_lstm (1024 blk) [+ zpart (256 blk)] ====
__global__ __launch_bounds__(256)
void lstm_merge_k(const float* __restrict__ in0, long bs0,
                  const float* __restrict__ in1,
                  const float* __restrict__ w, const float* __restrict__ bias,
                  const float* __restrict__ cprev,
                  float* __restrict__ hout, float* __restrict__ cout_,
                  const float* __restrict__ zh, const float* __restrict__ zc,
                  float* __restrict__ zdst,
                  const float* __restrict__ wt1, const float* __restrict__ bt1)
{
    __shared__ float lds[8 * 612];
    const int bid = blockIdx.x, b = blockIdx.z;
    if (bid < 1024) {
        lstm_dev(lds, bid & 31, bid >> 5, b, in0, bs0, in1, w, bias,
                 cprev, hout, cout_);
    } else {
        const int q = bid - 1024;
        zpart_dev(lds, q & 63, q >> 6, b, zh, zc, wt1, bt1, zdst);
    }
}

// ============ standalone zpart (t=9) =======================================
__global__ __launch_bounds__(256)
void zpart_k(const float* __restrict__ zh, const float* __restrict__ zc,
             float* __restrict__ zdst,
             const float* __restrict__ wt1, const float* __restrict__ bt1)
{
    __shared__ float lds[4 * 324];
    zpart_dev(lds, blockIdx.x, blockIdx.y, blockIdx.z, zh, zc, wt1, bt1, zdst);
}

// ============ merged dispatch: dec-LSTM1 split-K conv [+ zpart(s)] =========
__global__ __launch_bounds__(256)
void dec_merge_k(const float* __restrict__ hs1s,
                 const float* __restrict__ hb1, long hb1bs,
                 const float* __restrict__ w1,          // (4,65,3,3)
                 float* __restrict__ l1p, int nb,
                 const float* __restrict__ zc, float* __restrict__ zdst,
                 const float* __restrict__ wt1, const float* __restrict__ bt1)
{
    __shared__ float lds[4 * 324];
    const int bid = blockIdx.x, b = blockIdx.z;
    if (bid < 256) {
        const int tile = bid & 63, s = bid >> 6;
        const int ci0 = (s == 0) ? 0 : (s == 1) ? 17 : (s == 2) ? 33 : 49;
        const int cn  = (s == 0) ? 17 : 16;
        const int tid = threadIdx.x;
        const int tx = tid & 15, ty = tid >> 4;
        const int tileX = (tile & 7) << 4, tileY = (tile >> 3) << 4;
        int g0[2]; float m0[2];
#pragma unroll
        for (int i = 0; i < 2; i++) {
            const int lidx = tid + i * 256;
            const int r = lidx / 18, cc = lidx - r * 18;
            const int gy = tileY + r - 1, gx = tileX + cc - 1;
            const bool inb = (lidx < 324) && ((unsigned)gy < 128u) && ((unsigned)gx < 128u);
            g0[i] = inb ? gy * 128 + gx : 0;
            m0[i] = inb ? 1.f : 0.f;
        }
        float acc[4] = {0.f, 0.f, 0.f, 0.f};
        for (int cb = 0; cb < cn; cb += 4) {
            const int cmax = min(4, cn - cb);
            for (int cl = 0; cl < cmax; cl++) {
                const int ci = ci0 + cb + cl;
                const float* p = (ci < 64) ? hs1s + ((long)b * 64 + ci) * PX
                                           : hb1 + (long)b * hb1bs;
#pragma unroll
                for (int i = 0; i < 2; i++) {
                    const int lidx = tid + i * 256;
                    if (lidx < 324) lds[cl * 324 + lidx] = m0[i] * p[g0[i]];
                }
            }
            __syncthreads();
            for (int cl = 0; cl < cmax; cl++) {
                float r9[9];
#pragma unroll
                for (int dy = 0; dy < 3; dy++)
#pragma unroll
                    for (int dx = 0; dx < 3; dx++)
                        r9[dy * 3 + dx] = lds[cl * 324 + (ty + dy) * 18 + tx + dx];
                const int ci = ci0 + cb + cl;
#pragma unroll
                for (int j = 0; j < 4; j++) {
                    const float* wp = w1 + ((long)j * 65 + ci) * 9;
                    float a = acc[j];
#pragma unroll
                    for (int q = 0; q < 9; q++) a = fmaf(wp[q], r9[q], a);
                    acc[j] = a;
                }
            }
            __syncthreads();
        }
        const long opix = (long)(tileY + ty) * 128 + tileX + tx;
#pragma unroll
        for (int j = 0; j < 4; j++)
            l1p[(((long)s * nb + b) * 4 + j) * PX + opix] = acc[j];
    } else {
        const int q = bid - 256;
        zpart_dev(lds, q & 63, q >> 6, b, hs1s, zc, wt1, bt1, zdst);
    }
}

// ============ combine split-K LSTM gate partials -> h,c,out2 ===============
__global__ __launch_bounds__(256)
void combine_lstm_k(const float* __restrict__ pbuf, int nsl, int hidden,
                    const float* __restrict__ bias,
                    const float* __restrict__ cprev, long cpbs,
                    float* __restrict__ hout, long hobs,
                    float* __restrict__ cout_, long cobs,
                    float* __restrict__ hout2, long ho2bs, int nb)
{
    const long idx = (long)blockIdx.x * 256 + threadIdx.x;
    if (idx >= (long)nb * hidden * PX) return;
    const long px = idx & 16383;
    const long v = idx >> 14;
    const int hc = (int)(v % hidden), b = (int)(v / hidden);
    const int nco = 4 * hidden;
    float g4[4] = {0.f, 0.f, 0.f, 0.f};
    for (int s = 0; s < nsl; s++)
#pragma unroll
        for (int g = 0; g < 4; g++)
            g4[g] += pbuf[(((long)s * nb + b) * nco + g * hidden + hc) * PX + px];
    const float i_ = fast_sig(g4[0] + bias[hc]);
    const float f_ = fast_sig(g4[1] + bias[hidden + hc]);
    const float o_ = fast_sig(g4[2] + bias[2 * hidden + hc]);
    const float g_ = fast_tanh(g4[3] + bias[3 * hidden + hc]);
    const float cp = cprev[(long)b * cpbs + (long)hc * PX + px];
    const float c2 = f_ * cp + i_ * g_;
    const float h2 = o_ * fast_tanh(c2);
    hout[(long)b * hobs + (long)hc * PX + px] = h2;
    cout_[(long)b * cobs + (long)hc * PX + px] = c2;
    if (hout2) hout2[(long)b * ho2bs + (long)hc * PX + px] = h2;
}

// ============ phase-1 enc0 LSTM: direct fused conv (11 ch) + gates =========
__global__ __launch_bounds__(256)
void enc0_lstm_k(const float* __restrict__ x, int t, const float* __restrict__ A,
                 const float* __restrict__ hprev, const float* __restrict__ cprev,
                 const float* __restrict__ w, const float* __restrict__ bias,
                 float* __restrict__ hout, float* __restrict__ cout_)
{
    __shared__ float lds[4 * 324];
    const int tid = threadIdx.x;
    const int tx = tid & 15, ty = tid >> 4;
    const int tile = blockIdx.x, b = blockIdx.z;
    const int tileX = (tile & 7) << 4, tileY = (tile >> 3) << 4;
    int g0[2]; float m0[2]; float aTr[2][10];
#pragma unroll
    for (int i = 0; i < 2; i++) {
        const int lidx = tid + i * 256;
        const int r = lidx / 18, cc = lidx - r * 18;
        const int gy = tileY + r - 1, gx = tileX + cc - 1;
        const bool inb = (lidx < 324) && ((unsigned)gy < 128u) && ((unsigned)gx < 128u);
        g0[i] = inb ? gy * 128 + gx : 0;
        m0[i] = inb ? 1.f : 0.f;
    }
    float acc[4] = {0.f, 0.f, 0.f, 0.f};
    for (int cb = 0; cb < 11; cb += 4) {
        const int cmax = min(4, 11 - cb);
        for (int cl = 0; cl < cmax; cl++) {
            const int ci = cb + cl;
#pragma unroll
            for (int i = 0; i < 2; i++) {
                const int lidx = tid + i * 256;
                if (lidx < 324) {
                    float v;
                    if (ci < 10) {
                        v = x[(((long)b * T_ + t) * D_ + ci) * PX + g0[i]]
                            * A[((long)b * 10 + ci) * PX + g0[i]];
                    } else {
                        v = hprev[(long)b * PX + g0[i]];
                    }
                    lds[cl * 324 + lidx] = m0[i] * v;
                }
            }
        }
        __syncthreads();
        for (int cl = 0; cl < cmax; cl++) {
            float r9[9];
#pragma unroll
            for (int dy = 0; dy < 3; dy++)
#pragma unroll
                for (int dx = 0; dx < 3; dx++)
                    r9[dy * 3 + dx] = lds[cl * 324 + (ty + dy) * 18 + tx + dx];
            const int ci = cb + cl;
#pragma unroll
            for (int g = 0; g < 4; g++) {
                const float* wp = w + ((long)g * 11 + ci) * 9;
                float a = acc[g];
#pragma unroll
                for (int q = 0; q < 9; q++) a = fmaf(wp[q], r9[q], a);
                acc[g] = a;
            }
        }
        __syncthreads();
    }
    const long opix = (long)(tileY + ty) * 128 + tileX + tx;
    const float i_ = fast_sig(acc[0] + bias[0]);
    const float f_ = fast_sig(acc[1] + bias[1]);
    const float o_ = fast_sig(acc[2] + bias[2]);
    const float g_ = fast_tanh(acc[3] + bias[3]);
    const float cp = cprev[(long)b * PX + opix];
    const float c2 = f_ * cp + i_ * g_;
    const float h2 = o_ * fast_tanh(c2);
    hout[(long)b * PX + opix] = h2;
    cout_[(long)b * PX + opix] = c2;
}

// ============ fused input-attention score (phase 1, full batch) ============
// A == nullptr => scale 1 (t=0). co processed in 2 halves of 16 -> LDS 40KB.
__global__ __launch_bounds__(256)
void iattn_k(const float* __restrict__ x, const float* __restrict__ A,
             const float* __restrict__ h, const float* __restrict__ c,
             const float* __restrict__ wa1, const float* __restrict__ ba1,
             const float* __restrict__ wa2, const float* __restrict__ ba2,
             float* __restrict__ score)
{
    __shared__ float xl[12][400];              // 19.2 KB
    __shared__ float zl[16][324];              // 20.7 KB
    const int tid = threadIdx.x;
    const int tileX = (blockIdx.x & 7) << 4, tileY = (blockIdx.x >> 3) << 4;
    const int z = blockIdx.z;
    const int b = z & 7, k = z >> 3;

    // hoisted 20x20 staging geometry + per-thread A values (no LDS round-trip)
    int g0[2]; float m0[2]; float aTr[2];
#pragma unroll
    for (int i = 0; i < 2; i++) {
        const int lidx = tid + i * 256;
        const int r = lidx / 20, cc = lidx - r * 20;
        const int gy = tileY + r - 2, gx = tileX + cc - 2;
        const bool inb = (lidx < 400) && ((unsigned)gy < 128u) && ((unsigned)gx < 128u);
        g0[i] = inb ? gy * 128 + gx : 0;
        m0[i] = inb ? 1.f : 0.f;
        aTr[i] = A ? (m0[i] * A[((long)b * 10 + k) * PX + g0[i]]) : 1.f;
    }
    for (int ch = 0; ch < 12; ch++) {
        const float* p = (ch < 10) ? x + (((long)b * 10 + ch) * 10 + k) * PX
                       : (ch == 10) ? h + (long)b * PX : c + (long)b * PX;
#pragma unroll
        for (int i = 0; i < 2; i++) {
            const int lidx = tid + i * 256;
            if (lidx < 400) {
                float v = m0[i] * p[g0[i]];
                if (ch < 10) v *= aTr[i];
                xl[ch][lidx] = v;
            }
        }
    }
    __syncthreads();

    // conv1 positions (18x18 grid): i0 always valid, i1 iff tid < 68
    const int i0 = tid;
    const int i1 = tid + 256;
    const int zr0 = i0 / 18, zc0 = i0 - zr0 * 18;
    const int zr1 = (i1 < 324) ? i1 / 18 : 0;
    const int zc1 = (i1 < 324) ? i1 - zr1 * 18 : 0;
    const int gy0 = tileY + zr0 - 1, gx0 = tileX + zc0 - 1;
    const bool in0_ = (i0 < 324) && ((unsigned)gy0 < 128u) && ((unsigned)gx0 < 128u);
    const int gy1 = tileY + zr1 - 1, gx1 = tileX + zc1 - 1;
    const bool in1_ = (i1 < 324) && ((unsigned)gy1 < 128u) && ((unsigned)gx1 < 128u);

    const int tx = tid & 15, ty = tid >> 4;
    float sacc = ba2[0];

    for (int hf = 0; hf < 2; hf++) {
        float acc0[16], acc1[16];
#pragma unroll
        for (int co = 0; co < 16; co++) { acc0[co] = 0.f; acc1[co] = 0.f; }
        for (int ci = 0; ci < 12; ci++) {
            float wA[9], wB[9];
#pragma unroll
            for (int dy = 0; dy < 3; dy++)
#pragma unroll
                for (int dx = 0; dx < 3; dx++) {
                    wA[dy * 3 + dx] = xl[ci][(zr0 + dy) * 20 + zc0 + dx];
                    wB[dy * 3 + dx] = xl[ci][(zr1 + dy) * 20 + zc1 + dx];
                }
#pragma unroll
            for (int co = 0; co < 16; co++) {
                const float* wp = wa1 + ((long)(hf * 16 + co) * 12 + ci) * 9;
                float a0 = acc0[co], a1 = acc1[co];
#pragma unroll
                for (int q = 0; q < 9; q++) {
                    a0 = fmaf(wp[q], wA[q], a0);
                    a1 = fmaf(wp[q], wB[q], a1);
                }
                acc0[co] = a0; acc1[co] = a1;
            }
        }
        if (hf) __syncthreads();   // conv2 of half 0 done before zl overwrite
#pragma unroll
        for (int co = 0; co < 16; co++) {
            zl[co][i0] = in0_ ? fast_tanh(acc0[co] + ba1[hf * 16 + co]) : 0.f;
            if (i1 < 324) zl[co][i1] = in1_ ? fast_tanh(acc1[co] + ba1[hf * 16 + co]) : 0.f;
        }
        __syncthreads();
        for (int co = 0; co < 16; co++) {
            const float* wp = wa2 + (hf * 16 + co) * 9;
#pragma unroll
            for (int ky = 0; ky < 3; ky++)
#pragma unroll
                for (int kx = 0; kx < 3; kx++)
                    sacc = fmaf(wp[ky * 3 + kx], zl[co][(ty + ky) * 18 + tx + kx], sacc);
        }
    }
    score[((long)b * 10 + k) * PX + (long)(tileY + ty) * 128 + tileX + tx] = sacc;
}

// ============ softmax over 10 (+compound into A) ===========================
__global__ __launch_bounds__(256)
void softmax_mul_k(const float* __restrict__ s, float* __restrict__ A, int nb, int init)
{
    const long idx = (long)blockIdx.x * 256 + threadIdx.x;
    if (idx >= (long)nb * PX) return;
    const long b = idx >> 14, p = idx & 16383;
    const float* base = s + b * 10 * PX + p;
    float v[10]; float m = -1e30f;
#pragma unroll
    for (int t = 0; t < 10; t++) { v[t] = base[t * PX]; m = fmaxf(m, v[t]); }
    float sum = 0.f;
#pragma unroll
    for (int t = 0; t < 10; t++) { v[t] = fast_exp(v[t] - m); sum += v[t]; }
    const float r = __builtin_amdgcn_rcpf(sum);
    float* Ab = A + b * 10 * PX + p;
#pragma unroll
    for (int t = 0; t < 10; t++)
        Ab[t * PX] = init ? (v[t] * r) : (Ab[t * PX] * v[t] * r);
}

// ============ decoder attention score (y-part fused with cached Zpart) =====
// co processed in 2 halves of 16 -> LDS 22.3 KB -> ~7 blocks/CU.
__global__ __launch_bounds__(256)
void attn_fuse_k(const float* __restrict__ y, long ybs,
                 const float* __restrict__ zpart,
                 const float* __restrict__ wt1,
                 const float* __restrict__ wt2, const float* __restrict__ bt2,
                 float* __restrict__ score, int nb)
{
    __shared__ float ylds[400];
    __shared__ float zl[16][324];
    const int tid = threadIdx.x;
    const int tileX = (blockIdx.x & 7) << 4, tileY = (blockIdx.x >> 3) << 4;
    const int z = blockIdx.z;
    const int b = z % nb, t = z / nb;

#pragma unroll
    for (int i = 0; i < 2; i++) {
        const int lidx = tid + i * 256;
        if (lidx < 400) {
            const int r = lidx / 20, cc = lidx - r * 20;
            const int gy = tileY + r - 2, gx = tileX + cc - 2;
            const bool inb = ((unsigned)gy < 128u) && ((unsigned)gx < 128u);
            ylds[lidx] = inb ? y[(long)b * ybs + gy * 128 + gx] : 0.f;
        }
    }
    __syncthreads();

    const int i0 = tid, i1 = tid + 256;
    const int zr0 = i0 / 18, zc0 = i0 - zr0 * 18;
    const int zr1 = (i1 < 324) ? i1 / 18 : 0;
    const int zc1 = (i1 < 324) ? i1 - zr1 * 18 : 0;
    const int gy0 = tileY + zr0 - 1, gx0 = tileX + zc0 - 1;
    const bool in0_ = ((unsigned)gy0 < 128u) && ((unsigned)gx0 < 128u);
    const int gy1 = tileY + zr1 - 1, gx1 = tileX + zc1 - 1;
    const bool in1_ = (i1 < 324) && ((unsigned)gy1 < 128u) && ((unsigned)gx1 < 128u);
    const long pix0 = in0_ ? (long)gy0 * 128 + gx0 : 0;
    const long pix1 = in1_ ? (long)gy1 * 128 + gx1 : 0;
    const float* zp0 = zpart + ((long)t * nb + b) * 32 * PX;

    const int tx = tid & 15, ty = tid >> 4;
    float sacc = bt2[0];

    for (int hf = 0; hf < 2; hf++) {
        float yw0[9], yw1[9];
#pragma unroll
        for (int dy = 0; dy < 3; dy++)
#pragma unroll
            for (int dx = 0; dx < 3; dx++) {
                yw0[dy * 3 + dx] = ylds[(zr0 + dy) * 20 + zc0 + dx];
                yw1[dy * 3 + dx] = ylds[(zr1 + dy) * 20 + zc1 + dx];
            }
        if (hf) __syncthreads();
#pragma unroll 4
        for (int ch = 0; ch < 16; ch++) {
            const int cg = hf * 16 + ch;
            const float* wy = wt1 + (long)cg * 129 * 9;
            float s0 = zp0[(long)cg * PX + pix0];
            float s1 = (i1 < 324) ? zp0[(long)cg * PX + pix1] : 0.f;
#pragma unroll
            for (int q = 0; q < 9; q++) {
                s0 = fmaf(wy[q], yw0[q], s0);
                s1 = fmaf(wy[q], yw1[q], s1);
            }
            zl[ch][i0] = in0_ ? fast_tanh(s0) : 0.f;
            if (i1 < 324) zl[ch][i1] = in1_ ? fast_tanh(s1) : 0.f;
        }
        __syncthreads();
        for (int ch = 0; ch < 16; ch++) {
            const float* wp = wt2 + (hf * 16 + ch) * 9;
#pragma unroll
            for (int ky = 0; ky < 3; ky++)
#pragma unroll
                for (int kx = 0; kx < 3; kx++)
                    sacc = fmaf(wp[ky * 3 + kx], zl[ch][(ty + ky) * 18 + tx + kx], sacc);
        }
    }
    score[((long)b * 10 + t) * PX + (long)(tileY + ty) * 128 + tileX + tx] = sacc;
}

// ============ fused softmax + temporal weighted sum, ch-group split ========
__global__ __launch_bounds__(256)
void smax_wsum_k(const float* __restrict__ score, const float* __restrict__ hs1,
                 float* __restrict__ aht, int nb)
{
    const long idx = (long)blockIdx.x * 256 + threadIdx.x;
    if (idx >= (long)nb * PX) return;
    const long b = idx >> 14, p = idx & 16383;
    const int ch0 = blockIdx.y * 8;
    const float* base = score + b * 10 * PX + p;
    float v[10]; float m = -1e30f;
#pragma unroll
    for (int t = 0; t < 10; t++) { v[t] = base[t * PX]; m = fmaxf(m, v[t]); }
    float sum = 0.f;
#pragma unroll
    for (int t = 0; t < 10; t++) { v[t] = fast_exp(v[t] - m); sum += v[t]; }
    const float r = __builtin_amdgcn_rcpf(sum);
#pragma unroll
    for (int t = 0; t < 10; t++) v[t] *= r;
    const long slot1 = (long)nb * 64 * PX;
#pragma unroll
    for (int j = 0; j < 8; j++) {
        const int ch = ch0 + j;
        float a = 0.f;
#pragma unroll
        for (int t = 0; t < 10; t++)
            a += v[t] * hs1[t * slot1 + (b * 64 + ch) * PX + p];
        aht[(b * 64 + ch) * PX + p] = a;
    }
}

// ---------------------------------------------------------------------------
extern "C" void kernel_launch(void* const* d_in, const int* in_sizes, int n_in,
                              void* d_out, int out_size, void* d_ws, size_t ws_size,
                              hipStream_t stream)
{
    const float* x      = (const float*)d_in[0];
    const float* h0     = (const float*)d_in[1];
    const float* c0in   = (const float*)d_in[2];
    const float* h1     = (const float*)d_in[3];
    const float* c1     = (const float*)d_in[4];
    const float* w_enc0 = (const float*)d_in[5];
    const float* b_enc0 = (const float*)d_in[6];
    const float* w_enc1 = (const float*)d_in[7];
    const float* b_enc1 = (const float*)d_in[8];
    const float* w_dec0 = (const float*)d_in[9];
    const float* b_dec0 = (const float*)d_in[10];
    const float* w_dec1 = (const float*)d_in[11];
    const float* b_dec1 = (const float*)d_in[12];
    const float* wa1 = (const float*)d_in[13];
    const float* ba1 = (const float*)d_in[14];
    const float* wa2 = (const float*)d_in[15];
    const float* ba2 = (const float*)d_in[16];
    const float* wt1 = (const float*)d_in[17];
    const float* bt1 = (const float*)d_in[18];
    const float* wt2 = (const float*)d_in[19];
    const float* bt2 = (const float*)d_in[20];
    float* out = (float*)d_out;

    // ---- adaptive batch tile: need = (160 + 1188*nb)*PX*4 B ----
    int nb = 0;
    for (int cand = 8; cand >= 1; cand >>= 1) {
        const size_t need = (size_t)(160 + 1188 * cand) * PX * sizeof(float);
        if (need <= ws_size) { nb = cand; break; }
    }
    if (nb == 0) return;

    float* ws = (float*)d_ws;
    float* hs0 = ws;                      // [10][8][PX]
    float* cs0 = hs0 + 80 * PX;           // [10][8][PX]
    float* G   = cs0 + 80 * PX;
    // phase-1 aliases inside G
    float* A    = G;                      // [8][10][PX]
    float* sc1  = G + 80 * PX;            // [8][10][PX]
    // phase-2 per-group layout inside G
    const long slot1  = (long)nb * 64 * PX;
    float* hs1   = G;                                 // 10 * slot1
    float* cs1   = hs1 + 10 * slot1;                  // 2 * slot1 (ping-pong)
    float* zpart = cs1 + 2 * slot1;                   // [10][nb][32][PX]
    float* aht   = zpart + (long)10 * nb * 32 * PX;   // [nb][64][PX]
    float* l1p   = aht + (long)nb * 64 * PX;          // [4][nb][4][PX]
    float* hs0g  = l1p + (long)4 * nb * 4 * PX;       // [5][nb][PX]
    float* cs0g  = hs0g + (long)5 * nb * PX;          // [5][nb][PX]
    float* scD   = cs0g + (long)5 * nb * PX;          // [nb][10][PX]

    const dim3 blk(256);
    const long TDP = (long)T_ * D_ * PX;
    const long zslot = (long)nb * 32 * PX;

    // ================= phase 1: encoder layer 0, FULL batch =================
    for (int t = 0; t < 10; t++) {
        const float* hprev = (t == 0) ? h0 : hs0 + (long)(t - 1) * 8 * PX;
        const float* cprev = (t == 0) ? c0in : cs0 + (long)(t - 1) * 8 * PX;
        iattn_k<<<dim3(64, 1, 80), blk, 0, stream>>>(
            x, (t == 0) ? nullptr : A, hprev, cprev, wa1, ba1, wa2, ba2, sc1);
        softmax_mul_k<<<512, blk, 0, stream>>>(sc1, A, 8, t == 0);
        enc0_lstm_k<<<dim3(64, 1, 8), blk, 0, stream>>>(
            x, t, A, hprev, cprev, w_enc0, b_enc0,
            hs0 + (long)t * 8 * PX, cs0 + (long)t * 8 * PX);
    }

    // ================= phase 2: per batch-group =================
    for (int b0 = 0; b0 < 8; b0 += nb) {
        const float* xb  = x + (long)b0 * TDP;
        float* outb = out + (long)b0 * 5 * PX;

        // -------- encoder layer 1, with zpart(t-1) merged in ---------------
        for (int t = 0; t < 10; t++) {
            const float* hprev = (t == 0) ? h1 + (long)b0 * 64 * PX
                                          : hs1 + (long)(t - 1) * slot1;
            const float* cprev = (t == 0) ? c1 + (long)b0 * 64 * PX
                                          : cs1 + (long)((t - 1) & 1) * slot1;
            const int gx = (t == 0) ? 1024 : 1280;
            lstm_merge_k<<<dim3(gx, 1, nb), blk, 0, stream>>>(
                hs0 + (long)t * 8 * PX + (long)b0 * PX, PX,
                hprev, w_enc1, b_enc1, cprev,
                hs1 + (long)t * slot1, cs1 + (long)(t & 1) * slot1,
                (t == 0) ? nullptr : hs1 + (long)(t - 1) * slot1,
                (t == 0) ? nullptr : cs1 + (long)((t - 1) & 1) * slot1,
                (t == 0) ? nullptr : zpart + (long)(t - 1) * zslot,
                wt1, bt1);
        }
        zpart_k<<<dim3(64, 4, nb), blk, 0, stream>>>(
            hs1 + 9L * slot1, cs1 + slot1, zpart + 9L * zslot, wt1, bt1);

        // -------- decoder (5 steps) --------
        for (int s = 0; s < 5; s++) {
            const float* yptr; long ybs;
            if (s == 0) { yptr = xb + 9L * D_ * PX; ybs = TDP; }
            else        { yptr = hs0g + (long)(s - 1) * nb * PX; ybs = PX; }
            const float* hb1 = (s == 0) ? hs0 + 9L * 8 * PX + (long)b0 * PX
                                        : hs0g + (long)(s - 1) * nb * PX;
            const float* cb1 = (s == 0) ? cs0 + 9L * 8 * PX + (long)b0 * PX
                                        : cs0g + (long)(s - 1) * nb * PX;

            attn_fuse_k<<<dim3(64, 1, 10 * nb), blk, 0, stream>>>(
                yptr, ybs, zpart, wt1, wt2, bt2, scD, nb);
            smax_wsum_k<<<dim3((int)(((long)nb * PX + 255) / 256), 8), blk, 0, stream>>>(
                scD, hs1, aht, nb);

            // decoder LSTM 0 (no merged zpart: it depends on this kernel)
            lstm_merge_k<<<dim3(1024, 1, nb), blk, 0, stream>>>(
                yptr, ybs, aht, w_dec0, b_dec0,
                cs1 + (long)((s + 1) & 1) * slot1,
                hs1 + (long)s * slot1, cs1 + (long)(s & 1) * slot1,
                nullptr, nullptr, nullptr, wt1, bt1);

            // dec LSTM1 split-K conv + zpart(s) (skip zpart at s=4)
            const int gx2 = (s < 4) ? 512 : 256;
            dec_merge_k<<<dim3(gx2, 1, nb), blk, 0, stream>>>(
                hs1 + (long)s * slot1, hb1, PX, w_dec1, l1p, nb,
                cs1 + (long)(s & 1) * slot1, zpart + (long)s * zslot, wt1, bt1);
            combine_lstm_k<<<(int)(((long)nb * PX + 255) / 256), blk, 0, stream>>>(
                l1p, 4, 1, b_dec1, cb1, PX,
                hs0g + (long)s * nb * PX, PX,
                cs0g + (long)s * nb * PX, PX,
                outb + (long)s * PX, 5 * PX, nb);
        }
    }
}